// Round 4
// baseline (565.062 us; speedup 1.0000x reference)
//
#include <hip/hip_runtime.h>

#define N_NODES 100000
#define N_EDGES 1250000
#define D 64
#define BSH 6                  // 64 nodes per bucket
#define BNODES 64
#define NB 1563                // ceil(100000/64)
#define WS 68                  // LDS row stride in floats (4-aligned, breaks bank patterns)

typedef unsigned int u32;

// ---------------------------------------------------------------------------
// Bin edges by 64-node dst bucket. Packed word = (src<<6) | (dst&63)
// (src < 2^17, so 23 bits total). Bucket cursors padded to one per 128B line
// -> no line-level atomic serialization. 1563 write streams = 200KB of open
// lines, L2-resident -> writes accumulate to full lines (~5MB HBM, not 86MB).
// ---------------------------------------------------------------------------
__global__ void __launch_bounds__(256) k_bin(const int* __restrict__ ei,
                                             u32* __restrict__ bcnt,     // stride 32 u32
                                             u32* __restrict__ binned,
                                             int cap) {
    int idx = blockIdx.x * 256 + threadIdx.x;   // 4 edges per thread
    if (idx * 4 >= N_EDGES) return;             // N_EDGES % 4 == 0, no partial groups
    const int4* sp = (const int4*)ei;
    const int4* dp = (const int4*)(ei + N_EDGES);
    int4 s4 = sp[idx];
    int4 d4 = dp[idx];
    int ss[4] = {s4.x, s4.y, s4.z, s4.w};
    int dd[4] = {d4.x, d4.y, d4.z, d4.w};
#pragma unroll
    for (int u = 0; u < 4; ++u) {
        int b = dd[u] >> BSH;
        int dl = dd[u] & (BNODES - 1);
        u32 slot = atomicAdd(&bcnt[b << 5], 1u);
        if ((int)slot < cap)
            binned[(size_t)b * cap + slot] = ((u32)ss[u] << BSH) | (u32)dl;
    }
}

// ---------------------------------------------------------------------------
// Fused gather + mean + GEMM. One block per bucket (64 nodes).
// LDS: Wt[128][WS] both weight mats transposed (34.8KB) + Atile[64][WS]
// (17.4KB, reused: agg -> mean -> x self-tile) + deg -> 52.5KB, 3 blocks/CU.
// Edge phase: wave processes 4 edges/iter; x-row read 256B coalesced
// (L2/L3-served), ds_add_f32 into Atile[dl][lane] (2-way alias, free).
// ---------------------------------------------------------------------------
__global__ void __launch_bounds__(256) k_fused(const float* __restrict__ x,
                                               const float* __restrict__ wn,
                                               const float* __restrict__ wsf,
                                               const float* __restrict__ bias,
                                               const u32* __restrict__ bcnt,
                                               const u32* __restrict__ binned,
                                               int cap,
                                               float* __restrict__ out) {
    __shared__ float Wt[128 * WS];
    __shared__ float Atile[BNODES * WS];
    __shared__ u32 ldeg[BNODES];
    int tid = threadIdx.x;
    int b = blockIdx.x;
    int base = b << BSH;

    // Stage weights transposed: Wt[k][d] = wn[d][k]; rows 64..127 = ws.
    for (int i = tid; i < 4096; i += 256) {
        int d = i >> 6, k = i & 63;
        Wt[k * WS + d] = wn[i];
        Wt[(64 + k) * WS + d] = wsf[i];
    }
    for (int i = tid; i < BNODES * WS; i += 256) Atile[i] = 0.f;
    if (tid < BNODES) ldeg[tid] = 0;
    __syncthreads();

    // Edge accumulation.
    int cnt = min((int)bcnt[b << 5], cap);
    int lane = tid & 63, wave = tid >> 6;
    const uint4* bp = (const uint4*)(binned + (size_t)b * cap);
    for (int g = wave; g * 4 < cnt; g += 4) {
        uint4 w4 = bp[g];                       // broadcast 16B, 4 edges
        u32 wv[4] = {w4.x, w4.y, w4.z, w4.w};
        int e0 = g * 4;
#pragma unroll
        for (int u = 0; u < 4; ++u) {
            if (e0 + u < cnt) {
                int src = (int)(wv[u] >> BSH);
                int dl = (int)(wv[u] & (BNODES - 1));
                float v = x[(size_t)src * D + lane];
                atomicAdd(&Atile[dl * WS + lane], v);
                if (lane == 0) atomicAdd(&ldeg[dl], 1u);
            }
        }
    }
    __syncthreads();

    // Mean in place.
    for (int i = tid; i < BNODES * D; i += 256) {
        int n = i >> 6, k = i & 63;
        float dg = (float)max(ldeg[n], 1u);
        Atile[n * WS + k] /= dg;
    }
    __syncthreads();

    // GEMM: 4x4 micro-tile per thread over the 64x64 output tile.
    int tn = tid >> 4, td = tid & 15;
    int n0 = tn * 4, d0 = td * 4;
    float4 b4 = *(const float4*)&bias[d0];
    float acc[4][4];
#pragma unroll
    for (int i = 0; i < 4; ++i) {
        acc[i][0] = b4.x; acc[i][1] = b4.y; acc[i][2] = b4.z; acc[i][3] = b4.w;
    }

    // Half-1: neighbor term (A = mean tile, W rows 0..63).
#pragma unroll 4
    for (int kc = 0; kc < 16; ++kc) {
        float4 a[4], w[4];
#pragma unroll
        for (int i = 0; i < 4; ++i) a[i] = *(const float4*)&Atile[(n0 + i) * WS + kc * 4];
#pragma unroll
        for (int t = 0; t < 4; ++t) w[t] = *(const float4*)&Wt[(kc * 4 + t) * WS + d0];
#pragma unroll
        for (int i = 0; i < 4; ++i) {
            const float av[4] = {a[i].x, a[i].y, a[i].z, a[i].w};
#pragma unroll
            for (int t = 0; t < 4; ++t) {
                acc[i][0] += av[t] * w[t].x;
                acc[i][1] += av[t] * w[t].y;
                acc[i][2] += av[t] * w[t].z;
                acc[i][3] += av[t] * w[t].w;
            }
        }
    }
    __syncthreads();   // half-1 done reading Atile

    // Stage x self-tile into the same buffer.
    for (int q = tid; q < BNODES * 16; q += 256) {
        int n = q >> 4, k0 = (q & 15) * 4;
        int node = base + n;
        float4 v = make_float4(0.f, 0.f, 0.f, 0.f);
        if (node < N_NODES) v = *(const float4*)&x[(size_t)node * D + k0];
        *(float4*)&Atile[n * WS + k0] = v;
    }
    __syncthreads();

    // Half-2: self term (W rows 64..127).
#pragma unroll 4
    for (int kc = 0; kc < 16; ++kc) {
        float4 a[4], w[4];
#pragma unroll
        for (int i = 0; i < 4; ++i) a[i] = *(const float4*)&Atile[(n0 + i) * WS + kc * 4];
#pragma unroll
        for (int t = 0; t < 4; ++t) w[t] = *(const float4*)&Wt[(64 + kc * 4 + t) * WS + d0];
#pragma unroll
        for (int i = 0; i < 4; ++i) {
            const float av[4] = {a[i].x, a[i].y, a[i].z, a[i].w};
#pragma unroll
            for (int t = 0; t < 4; ++t) {
                acc[i][0] += av[t] * w[t].x;
                acc[i][1] += av[t] * w[t].y;
                acc[i][2] += av[t] * w[t].z;
                acc[i][3] += av[t] * w[t].w;
            }
        }
    }

    // Store.
#pragma unroll
    for (int i = 0; i < 4; ++i) {
        int node = base + n0 + i;
        if (node < N_NODES) {
            float4 o = make_float4(acc[i][0], acc[i][1], acc[i][2], acc[i][3]);
            *(float4*)&out[(size_t)node * D + d0] = o;
        }
    }
}

extern "C" void kernel_launch(void* const* d_in, const int* in_sizes, int n_in,
                              void* d_out, int out_size, void* d_ws, size_t ws_size,
                              hipStream_t stream) {
    const float* x = (const float*)d_in[0];
    const int* ei = (const int*)d_in[1];
    const float* wn = (const float*)d_in[2];
    const float* wsf = (const float*)d_in[3];
    const float* bias = (const float*)d_in[4];
    float* out = (float*)d_out;

    u32* bcnt = (u32*)d_ws;                 // NB * 32 words (line-padded counters)
    u32* binned = bcnt + (size_t)NB * 32;

    // Capacity per bucket from available workspace (mean fill = 800; 1024 is +8 sigma).
    size_t avail = ws_size / 4 - (size_t)NB * 32;
    size_t capz = (avail / NB) & ~(size_t)3;
    int cap = (int)(capz < 1024 ? capz : 1024);

    hipMemsetAsync(bcnt, 0, (size_t)NB * 32 * sizeof(u32), stream);
    k_bin<<<(N_EDGES / 4 + 255) / 256, 256, 0, stream>>>(ei, bcnt, binned, cap);
    k_fused<<<NB, 256, 0, stream>>>(x, wn, wsf, bias, bcnt, binned, cap, out);
}

// Round 5
// 169.035 us; speedup vs baseline: 3.3429x; 3.3429x over previous
//
#include <hip/hip_runtime.h>

#define N_NODES 100000
#define N_EDGES 1250000
#define D 64
#define BSH 6                  // 64 nodes per bucket
#define BNODES 64
#define NB 1563                // ceil(100000/64)
#define WS 68                  // LDS row stride (floats) for GEMM tiles

typedef unsigned int u32;

// ---------------------------------------------------------------------------
// Bin edges by 64-node dst bucket. Packed word = (src<<6) | (dst&63).
// 1563 write streams (~200KB of open lines, L2-resident) -> writes coalesce
// into full lines (~5-7MB HBM), unlike per-node fill (100K streams, 86MB).
// Cursors padded to one per 128B line.
// ---------------------------------------------------------------------------
__global__ void __launch_bounds__(256) k_bin(const int* __restrict__ ei,
                                             u32* __restrict__ bcnt,     // stride-32 u32 counters
                                             u32* __restrict__ binned,
                                             int cap) {
    int idx = blockIdx.x * 256 + threadIdx.x;   // 4 edges per thread
    if (idx * 4 >= N_EDGES) return;             // N_EDGES % 4 == 0
    const int4* sp = (const int4*)ei;
    const int4* dp = (const int4*)(ei + N_EDGES);
    int4 s4 = sp[idx];
    int4 d4 = dp[idx];
    int ss[4] = {s4.x, s4.y, s4.z, s4.w};
    int dd[4] = {d4.x, d4.y, d4.z, d4.w};
#pragma unroll
    for (int u = 0; u < 4; ++u) {
        int b = dd[u] >> BSH;
        u32 slot = atomicAdd(&bcnt[b << 5], 1u);
        if ((int)slot < cap)
            binned[(size_t)b * cap + slot] = ((u32)ss[u] << BSH) | (u32)(dd[u] & (BNODES - 1));
    }
}

// ---------------------------------------------------------------------------
// Per-bucket counting sort, in place in the bucket's own segment.
// Emits per-node absolute offsets into `binned` and per-node degree.
// Replaces: k_count + 3-kernel global scan + k_fill.
// ---------------------------------------------------------------------------
__global__ void __launch_bounds__(256) k_sort(u32* __restrict__ binned,
                                              const u32* __restrict__ bcnt,
                                              int cap,
                                              u32* __restrict__ offs,
                                              u32* __restrict__ deg) {
    __shared__ u32 eh[1024];       // cap <= 1024
    __shared__ u32 hist[BNODES];
    __shared__ u32 cur[BNODES];
    int tid = threadIdx.x;
    int b = blockIdx.x;
    int cnt = min((int)bcnt[b << 5], cap);
    u32* seg = binned + (size_t)b * cap;

    if (tid < BNODES) hist[tid] = 0;
    __syncthreads();
    for (int i = tid; i < cnt; i += 256) {
        u32 w = seg[i];
        eh[i] = w;
        atomicAdd(&hist[w & (BNODES - 1)], 1u);
    }
    __syncthreads();
    if (tid < BNODES) {            // wave 0: 64-wide shfl exclusive prefix
        u32 v = hist[tid];
        u32 s = v;
#pragma unroll
        for (int off = 1; off < 64; off <<= 1) {
            u32 n = __shfl_up(s, off, 64);
            if (tid >= off) s += n;
        }
        u32 excl = s - v;
        cur[tid] = excl;
        int node = (b << BSH) + tid;
        if (node < N_NODES) {
            offs[node] = (u32)((size_t)b * cap + excl);   // absolute index into binned
            deg[node] = v;
        }
    }
    __syncthreads();
    for (int i = tid; i < cnt; i += 256) {   // all reads done (eh); write sorted srcs
        u32 w = eh[i];
        u32 p = atomicAdd(&cur[w & (BNODES - 1)], 1u);
        seg[p] = w >> BSH;                   // plain src id now
    }
}

// ---------------------------------------------------------------------------
// Gather: one wave per node, lane = feature. 100K node-waves -> full
// occupancy, ~4 loads in flight per wave. x (25.6MB) is L2/L3-served.
// Writes mean-agg into d_out.
// ---------------------------------------------------------------------------
__global__ void __launch_bounds__(256) k_gather(const float* __restrict__ x,
                                                const u32* __restrict__ binned,
                                                const u32* __restrict__ offs,
                                                const u32* __restrict__ deg,
                                                float* __restrict__ agg) {
    int tid = blockIdx.x * 256 + threadIdx.x;
    int node = tid >> 6;
    int d = tid & 63;
    if (node >= N_NODES) return;
    u32 o0 = offs[node];
    u32 dg = deg[node];
    u32 o1 = o0 + dg;
    float s = 0.f;
    u32 j = o0;
    for (; j + 3 < o1; j += 4) {             // 4 independent loads in flight
        u32 s0 = binned[j], s1 = binned[j + 1], s2 = binned[j + 2], s3 = binned[j + 3];
        float v0 = x[(size_t)s0 * D + d];
        float v1 = x[(size_t)s1 * D + d];
        float v2 = x[(size_t)s2 * D + d];
        float v3 = x[(size_t)s3 * D + d];
        s += v0; s += v1; s += v2; s += v3;
    }
    for (; j < o1; ++j) s += x[(size_t)binned[j] * D + d];
    agg[(size_t)node * D + d] = s / (float)max(dg, 1u);
}

// ---------------------------------------------------------------------------
// Transform GEMM: C[100K x 64] = [agg | x] (100K x 128) @ [WnT; WsT] + b.
// Block = 64 nodes, 256 threads, 4x4 micro-tile, float4-vectorized staging.
// In-place on d_out (block reads only its own 64 rows before storing).
// ---------------------------------------------------------------------------
__global__ void __launch_bounds__(256) k_gemm(const float* __restrict__ x,
                                              const float* __restrict__ wn,
                                              const float* __restrict__ wsf,
                                              const float* __restrict__ bias,
                                              float* __restrict__ io) {
    __shared__ float At[128 * WS];   // [k][node]: k 0..63 agg, 64..127 x
    __shared__ float Wt[128 * WS];   // [k][dout]: k 0..63 wn,  64..127 ws
    int tid = threadIdx.x;
    int base = blockIdx.x * 64;

    const float4* iop = (const float4*)io;
    const float4* xp  = (const float4*)x;
    const float4* wnp = (const float4*)wn;
    const float4* wsp = (const float4*)wsf;
    for (int i = tid; i < 1024; i += 256) {
        int r = i >> 4;            // node-in-tile / weight out-row
        int q = i & 15;
        int k4 = q * 4;
        int node = base + r;
        float4 va = make_float4(0.f, 0.f, 0.f, 0.f), vx = va;
        if (node < N_NODES) {
            va = iop[(size_t)node * 16 + q];
            vx = xp[(size_t)node * 16 + q];
        }
        float4 w1 = wnp[r * 16 + q];
        float4 w2 = wsp[r * 16 + q];
        At[(k4 + 0) * WS + r] = va.x; At[(k4 + 1) * WS + r] = va.y;
        At[(k4 + 2) * WS + r] = va.z; At[(k4 + 3) * WS + r] = va.w;
        At[(64 + k4 + 0) * WS + r] = vx.x; At[(64 + k4 + 1) * WS + r] = vx.y;
        At[(64 + k4 + 2) * WS + r] = vx.z; At[(64 + k4 + 3) * WS + r] = vx.w;
        Wt[(k4 + 0) * WS + r] = w1.x; Wt[(k4 + 1) * WS + r] = w1.y;
        Wt[(k4 + 2) * WS + r] = w1.z; Wt[(k4 + 3) * WS + r] = w1.w;
        Wt[(64 + k4 + 0) * WS + r] = w2.x; Wt[(64 + k4 + 1) * WS + r] = w2.y;
        Wt[(64 + k4 + 2) * WS + r] = w2.z; Wt[(64 + k4 + 3) * WS + r] = w2.w;
    }
    __syncthreads();

    int tn = tid >> 4, td = tid & 15;
    int n0 = tn * 4, d0 = td * 4;
    float4 b4 = *(const float4*)&bias[d0];
    float acc[4][4];
#pragma unroll
    for (int i = 0; i < 4; ++i) {
        acc[i][0] = b4.x; acc[i][1] = b4.y; acc[i][2] = b4.z; acc[i][3] = b4.w;
    }

#pragma unroll 8
    for (int k = 0; k < 128; ++k) {
        float4 a4 = *(const float4*)&At[k * WS + n0];
        float4 w4 = *(const float4*)&Wt[k * WS + d0];
        float a[4] = {a4.x, a4.y, a4.z, a4.w};
        float w[4] = {w4.x, w4.y, w4.z, w4.w};
#pragma unroll
        for (int i = 0; i < 4; ++i)
#pragma unroll
            for (int j = 0; j < 4; ++j) acc[i][j] += a[i] * w[j];
    }

#pragma unroll
    for (int i = 0; i < 4; ++i) {
        int node = base + n0 + i;
        if (node < N_NODES) {
            float4 o = make_float4(acc[i][0], acc[i][1], acc[i][2], acc[i][3]);
            *(float4*)&io[(size_t)node * D + d0] = o;
        }
    }
}

extern "C" void kernel_launch(void* const* d_in, const int* in_sizes, int n_in,
                              void* d_out, int out_size, void* d_ws, size_t ws_size,
                              hipStream_t stream) {
    const float* x = (const float*)d_in[0];
    const int* ei = (const int*)d_in[1];
    const float* wn = (const float*)d_in[2];
    const float* wsf = (const float*)d_in[3];
    const float* bias = (const float*)d_in[4];
    float* out = (float*)d_out;

    // Workspace layout (u32): offs[100000] deg[100000] bcnt[NB*32] binned[NB*cap]
    u32* offs = (u32*)d_ws;
    u32* deg = offs + N_NODES;
    u32* bcnt = deg + N_NODES;
    u32* binned = bcnt + (size_t)NB * 32;

    size_t fixed = 2 * (size_t)N_NODES + (size_t)NB * 32;
    size_t avail = ws_size / 4 - fixed;
    size_t capz = (avail / NB) & ~(size_t)3;
    int cap = (int)(capz < 1024 ? capz : 1024);   // mean fill 800, max ~940

    hipMemsetAsync(bcnt, 0, (size_t)NB * 32 * sizeof(u32), stream);
    k_bin<<<(N_EDGES / 4 + 255) / 256, 256, 0, stream>>>(ei, bcnt, binned, cap);
    k_sort<<<NB, 256, 0, stream>>>(binned, bcnt, cap, offs, deg);
    k_gather<<<(N_NODES * 64) / 256, 256, 0, stream>>>(x, binned, offs, deg, out);
    k_gemm<<<(N_NODES + 63) / 64, 256, 0, stream>>>(x, wn, wsf, bias, out);
}

// Round 6
// 140.820 us; speedup vs baseline: 4.0127x; 1.2004x over previous
//
#include <hip/hip_runtime.h>

#define N_NODES 100000
#define N_EDGES 1250000
#define D 64
#define BSH 6                  // 64 nodes per bucket
#define BNODES 64
#define NB 1563                // ceil(100000/64)
#define WS 68                  // LDS row stride (floats) for GEMM tiles
#define BIN_BLOCKS 128
#define BIN_CHUNK ((N_EDGES + BIN_BLOCKS - 1) / BIN_BLOCKS)   // 9766

typedef unsigned int u32;

// ---------------------------------------------------------------------------
// x (fp32) -> bf16 packed 2/word, RNE. 8 floats per thread.
// ---------------------------------------------------------------------------
__global__ void __launch_bounds__(256) k_tobf16(const float* __restrict__ x,
                                                u32* __restrict__ x16) {
    int i = blockIdx.x * 256 + threadIdx.x;
    size_t base = (size_t)i * 8;
    if (base >= (size_t)N_NODES * D) return;
    const float4* xp = (const float4*)(x + base);
    float4 f0 = xp[0], f1 = xp[1];
    float fs[8] = {f0.x, f0.y, f0.z, f0.w, f1.x, f1.y, f1.z, f1.w};
    u32 w[4];
#pragma unroll
    for (int t = 0; t < 4; ++t) {
        u32 a = __float_as_uint(fs[2 * t]);
        u32 b = __float_as_uint(fs[2 * t + 1]);
        a = (a + 0x7fffu + ((a >> 16) & 1u)) >> 16;   // RNE to bf16
        b = (b + 0x7fffu + ((b >> 16) & 1u)) >> 16;
        w[t] = a | (b << 16);
    }
    *(uint4*)(x16 + base / 2) = make_uint4(w[0], w[1], w[2], w[3]);
}

// ---------------------------------------------------------------------------
// Binning, LDS-privatized two-pass. 128 blocks, each owns a ~9766-edge chunk:
// pass 1 LDS histogram over all 1563 buckets; reserve global ranges with ONE
// atomicAdd per (block,bucket); pass 2 scatter into reserved slots.
// Global same-address atomic chains: 800-deep -> ~115-deep (and only 180K ops).
// ---------------------------------------------------------------------------
__global__ void __launch_bounds__(256) k_bin2(const int* __restrict__ ei,
                                              u32* __restrict__ bcnt,
                                              u32* __restrict__ binned,
                                              int cap) {
    __shared__ u32 hist[NB];
    __shared__ u32 rbase[NB];
    int tid = threadIdx.x;
    int e0 = blockIdx.x * BIN_CHUNK;
    int e1 = min(e0 + BIN_CHUNK, N_EDGES);
    const int* dstp = ei + N_EDGES;

    for (int i = tid; i < NB; i += 256) hist[i] = 0;
    __syncthreads();
    for (int e = e0 + tid; e < e1; e += 256)
        atomicAdd(&hist[dstp[e] >> BSH], 1u);
    __syncthreads();
    for (int i = tid; i < NB; i += 256) {
        u32 h = hist[i];
        rbase[i] = h ? atomicAdd(&bcnt[i], h) : 0u;
        hist[i] = 0;               // becomes local cursor
    }
    __syncthreads();
    for (int e = e0 + tid; e < e1; e += 256) {
        int d = dstp[e];
        int s = ei[e];
        int b = d >> BSH;
        u32 loc = atomicAdd(&hist[b], 1u);
        u32 slot = rbase[b] + loc;
        if (slot < (u32)cap)
            binned[(size_t)b * cap + slot] = ((u32)s << BSH) | (u32)(d & (BNODES - 1));
    }
}

// ---------------------------------------------------------------------------
// Per-bucket counting sort, in place. Emits per-node absolute offsets + degree.
// ---------------------------------------------------------------------------
__global__ void __launch_bounds__(256) k_sort(u32* __restrict__ binned,
                                              const u32* __restrict__ bcnt,
                                              int cap,
                                              u32* __restrict__ offs,
                                              u32* __restrict__ deg) {
    __shared__ u32 eh[1024];
    __shared__ u32 hist[BNODES];
    __shared__ u32 cur[BNODES];
    int tid = threadIdx.x;
    int b = blockIdx.x;
    int cnt = min((int)bcnt[b], cap);
    u32* seg = binned + (size_t)b * cap;

    if (tid < BNODES) hist[tid] = 0;
    __syncthreads();
    for (int i = tid; i < cnt; i += 256) {
        u32 w = seg[i];
        eh[i] = w;
        atomicAdd(&hist[w & (BNODES - 1)], 1u);
    }
    __syncthreads();
    if (tid < BNODES) {
        u32 v = hist[tid];
        u32 s = v;
#pragma unroll
        for (int off = 1; off < 64; off <<= 1) {
            u32 n = __shfl_up(s, off, 64);
            if (tid >= off) s += n;
        }
        u32 excl = s - v;
        cur[tid] = excl;
        int node = (b << BSH) + tid;
        if (node < N_NODES) {
            offs[node] = (u32)((size_t)b * cap + excl);
            deg[node] = v;
        }
    }
    __syncthreads();
    for (int i = tid; i < cnt; i += 256) {
        u32 w = eh[i];
        u32 p = atomicAdd(&cur[w & (BNODES - 1)], 1u);
        seg[p] = w >> BSH;
    }
}

// ---------------------------------------------------------------------------
// Gather, bf16 x. One wave per node; half-wave per edge (lane reads one
// bf16x2 word = 2 features); 8 edges per main iter = 4 loads in flight/lane.
// Cross-half combine via shfl_xor(32). Writes fp32 mean-agg to d_out.
// ---------------------------------------------------------------------------
__global__ void __launch_bounds__(256) k_gather16(const u32* __restrict__ x16,
                                                  const u32* __restrict__ binned,
                                                  const u32* __restrict__ offs,
                                                  const u32* __restrict__ deg,
                                                  float* __restrict__ agg) {
    int tid = blockIdx.x * 256 + threadIdx.x;
    int node = tid >> 6;
    if (node >= N_NODES) return;
    int lane = threadIdx.x & 63;
    int sub = lane >> 5;
    int pr = lane & 31;
    u32 o0 = offs[node], dg = deg[node];
    u32 o1 = o0 + dg;
    float a0 = 0.f, a1 = 0.f;
    u32 j = o0;
    for (; j + 8 <= o1; j += 8) {
        u32 e[4], wv[4];
#pragma unroll
        for (int t = 0; t < 4; ++t) e[t] = binned[j + 2 * t + sub];
#pragma unroll
        for (int t = 0; t < 4; ++t) wv[t] = x16[(size_t)e[t] * 32 + pr];
#pragma unroll
        for (int t = 0; t < 4; ++t) {
            a0 += __uint_as_float(wv[t] << 16);
            a1 += __uint_as_float(wv[t] & 0xffff0000u);
        }
    }
    for (; j < o1; j += 2) {
        u32 idxe = j + sub;
        bool ok = idxe < o1;
        u32 e = binned[ok ? idxe : j];
        u32 w = x16[(size_t)e * 32 + pr];
        float m = ok ? 1.f : 0.f;
        a0 += m * __uint_as_float(w << 16);
        a1 += m * __uint_as_float(w & 0xffff0000u);
    }
    a0 += __shfl_xor(a0, 32);
    a1 += __shfl_xor(a1, 32);
    if (sub == 0) {
        float inv = 1.0f / (float)max(dg, 1u);
        *(float2*)&agg[(size_t)node * D + 2 * pr] = make_float2(a0 * inv, a1 * inv);
    }
}

// ---------------------------------------------------------------------------
// Gather fallback, fp32 x (used only if ws too small for x16). 8-deep ILP.
// ---------------------------------------------------------------------------
__global__ void __launch_bounds__(256) k_gather32(const float* __restrict__ x,
                                                  const u32* __restrict__ binned,
                                                  const u32* __restrict__ offs,
                                                  const u32* __restrict__ deg,
                                                  float* __restrict__ agg) {
    int tid = blockIdx.x * 256 + threadIdx.x;
    int node = tid >> 6;
    int d = tid & 63;
    if (node >= N_NODES) return;
    u32 o0 = offs[node], dg = deg[node];
    u32 o1 = o0 + dg;
    float s = 0.f;
    u32 j = o0;
    for (; j + 8 <= o1; j += 8) {
        u32 e[8];
        float v[8];
#pragma unroll
        for (int t = 0; t < 8; ++t) e[t] = binned[j + t];
#pragma unroll
        for (int t = 0; t < 8; ++t) v[t] = x[(size_t)e[t] * D + d];
#pragma unroll
        for (int t = 0; t < 8; ++t) s += v[t];
    }
    for (; j < o1; ++j) s += x[(size_t)binned[j] * D + d];
    agg[(size_t)node * D + d] = s / (float)max(dg, 1u);
}

// ---------------------------------------------------------------------------
// Transform GEMM: C[100K x 64] = [agg | x] @ [WnT; WsT] + b. In place on d_out.
// ---------------------------------------------------------------------------
__global__ void __launch_bounds__(256) k_gemm(const float* __restrict__ x,
                                              const float* __restrict__ wn,
                                              const float* __restrict__ wsf,
                                              const float* __restrict__ bias,
                                              float* __restrict__ io) {
    __shared__ float At[128 * WS];
    __shared__ float Wt[128 * WS];
    int tid = threadIdx.x;
    int base = blockIdx.x * 64;

    const float4* iop = (const float4*)io;
    const float4* xp  = (const float4*)x;
    const float4* wnp = (const float4*)wn;
    const float4* wsp = (const float4*)wsf;
    for (int i = tid; i < 1024; i += 256) {
        int r = i >> 4;
        int q = i & 15;
        int k4 = q * 4;
        int node = base + r;
        float4 va = make_float4(0.f, 0.f, 0.f, 0.f), vx = va;
        if (node < N_NODES) {
            va = iop[(size_t)node * 16 + q];
            vx = xp[(size_t)node * 16 + q];
        }
        float4 w1 = wnp[r * 16 + q];
        float4 w2 = wsp[r * 16 + q];
        At[(k4 + 0) * WS + r] = va.x; At[(k4 + 1) * WS + r] = va.y;
        At[(k4 + 2) * WS + r] = va.z; At[(k4 + 3) * WS + r] = va.w;
        At[(64 + k4 + 0) * WS + r] = vx.x; At[(64 + k4 + 1) * WS + r] = vx.y;
        At[(64 + k4 + 2) * WS + r] = vx.z; At[(64 + k4 + 3) * WS + r] = vx.w;
        Wt[(k4 + 0) * WS + r] = w1.x; Wt[(k4 + 1) * WS + r] = w1.y;
        Wt[(k4 + 2) * WS + r] = w1.z; Wt[(k4 + 3) * WS + r] = w1.w;
        Wt[(64 + k4 + 0) * WS + r] = w2.x; Wt[(64 + k4 + 1) * WS + r] = w2.y;
        Wt[(64 + k4 + 2) * WS + r] = w2.z; Wt[(64 + k4 + 3) * WS + r] = w2.w;
    }
    __syncthreads();

    int tn = tid >> 4, td = tid & 15;
    int n0 = tn * 4, d0 = td * 4;
    float4 b4 = *(const float4*)&bias[d0];
    float acc[4][4];
#pragma unroll
    for (int i = 0; i < 4; ++i) {
        acc[i][0] = b4.x; acc[i][1] = b4.y; acc[i][2] = b4.z; acc[i][3] = b4.w;
    }
#pragma unroll 8
    for (int k = 0; k < 128; ++k) {
        float4 a4 = *(const float4*)&At[k * WS + n0];
        float4 w4 = *(const float4*)&Wt[k * WS + d0];
        float a[4] = {a4.x, a4.y, a4.z, a4.w};
        float w[4] = {w4.x, w4.y, w4.z, w4.w};
#pragma unroll
        for (int i = 0; i < 4; ++i)
#pragma unroll
            for (int j = 0; j < 4; ++j) acc[i][j] += a[i] * w[j];
    }
#pragma unroll
    for (int i = 0; i < 4; ++i) {
        int node = base + n0 + i;
        if (node < N_NODES) {
            *(float4*)&io[(size_t)node * D + d0] =
                make_float4(acc[i][0], acc[i][1], acc[i][2], acc[i][3]);
        }
    }
}

extern "C" void kernel_launch(void* const* d_in, const int* in_sizes, int n_in,
                              void* d_out, int out_size, void* d_ws, size_t ws_size,
                              hipStream_t stream) {
    const float* x = (const float*)d_in[0];
    const int* ei = (const int*)d_in[1];
    const float* wn = (const float*)d_in[2];
    const float* wsf = (const float*)d_in[3];
    const float* bias = (const float*)d_in[4];
    float* out = (float*)d_out;

    // ws layout (u32): offs[100000] deg[100000] bcnt[NB pad16] [x16] binned
    u32* offs = (u32*)d_ws;
    u32* deg = offs + N_NODES;
    u32* bcnt = deg + N_NODES;
    u32* after_bcnt = bcnt + ((NB + 15) & ~15);
    size_t fixed = 2 * (size_t)N_NODES + ((NB + 15) & ~15);
    size_t avail = ws_size / 4 - fixed;
    const size_t X16W = (size_t)N_NODES * (D / 2);   // 3.2M words

    bool bf16 = false;
    int cap = 1024;
    u32 *x16 = nullptr, *binned = nullptr;
    if (avail >= X16W + (size_t)NB * 1024) {
        bf16 = true;
        x16 = after_bcnt;
        binned = x16 + X16W;
    } else {
        size_t capz = (avail / NB) & ~(size_t)3;
        cap = (int)(capz < 1024 ? capz : 1024);
        binned = after_bcnt;
    }

    hipMemsetAsync(bcnt, 0, ((NB + 15) & ~15) * sizeof(u32), stream);
    if (bf16)
        k_tobf16<<<(N_NODES * D / 8 + 255) / 256, 256, 0, stream>>>(x, x16);
    k_bin2<<<BIN_BLOCKS, 256, 0, stream>>>(ei, bcnt, binned, cap);
    k_sort<<<NB, 256, 0, stream>>>(binned, bcnt, cap, offs, deg);
    if (bf16)
        k_gather16<<<(N_NODES * 64) / 256, 256, 0, stream>>>(x16, binned, offs, deg, out);
    else
        k_gather32<<<(N_NODES * 64) / 256, 256, 0, stream>>>(x, binned, offs, deg, out);
    k_gemm<<<(N_NODES + 63) / 64, 256, 0, stream>>>(x, wn, wsf, bias, out);
}

// Round 7
// 135.573 us; speedup vs baseline: 4.1680x; 1.0387x over previous
//
#include <hip/hip_runtime.h>

#define N_NODES 100000
#define N_EDGES 1250000
#define D 64
#define BSH 6                  // 64 nodes per bucket
#define BNODES 64
#define NB 1563                // ceil(100000/64)
#define WSW 68                 // LDS row stride for W tiles (272B, 16B-aligned)
#define G 512                  // binning blocks
#define CHUNK ((N_EDGES + G - 1) / G)          // 2442
#define BIN_BLOCKS 128
#define BIN_CHUNK ((N_EDGES + BIN_BLOCKS - 1) / BIN_BLOCKS)

typedef unsigned int u32;

// ---------------------------------------------------------------------------
// x (fp32) -> bf16 packed 2/word, RNE.
// ---------------------------------------------------------------------------
__global__ void __launch_bounds__(256) k_tobf16(const float* __restrict__ x,
                                                u32* __restrict__ x16) {
    int i = blockIdx.x * 256 + threadIdx.x;
    size_t base = (size_t)i * 8;
    if (base >= (size_t)N_NODES * D) return;
    const float4* xp = (const float4*)(x + base);
    float4 f0 = xp[0], f1 = xp[1];
    float fs[8] = {f0.x, f0.y, f0.z, f0.w, f1.x, f1.y, f1.z, f1.w};
    u32 w[4];
#pragma unroll
    for (int t = 0; t < 4; ++t) {
        u32 a = __float_as_uint(fs[2 * t]);
        u32 b = __float_as_uint(fs[2 * t + 1]);
        a = (a + 0x7fffu + ((a >> 16) & 1u)) >> 16;
        b = (b + 0x7fffu + ((b >> 16) & 1u)) >> 16;
        w[t] = a | (b << 16);
    }
    *(uint4*)(x16 + base / 2) = make_uint4(w[0], w[1], w[2], w[3]);
}

// ---------------------------------------------------------------------------
// Deterministic binning pass A: per-block LDS histogram -> ghist[g][b]
// (coalesced 1563-word row per block). No global atomics.
// ---------------------------------------------------------------------------
__global__ void __launch_bounds__(256) k_hist(const int* __restrict__ ei,
                                              u32* __restrict__ ghist) {
    __shared__ u32 hist[NB];
    int tid = threadIdx.x;
    int g = blockIdx.x;
    int e0 = g * CHUNK, e1 = min(e0 + CHUNK, N_EDGES);
    const int* dstp = ei + N_EDGES;
    for (int i = tid; i < NB; i += 256) hist[i] = 0;
    __syncthreads();
    for (int e = e0 + tid; e < e1; e += 256)
        atomicAdd(&hist[dstp[e] >> BSH], 1u);
    __syncthreads();
    for (int i = tid; i < NB; i += 256)
        ghist[(size_t)g * NB + i] = hist[i];
}

// ---------------------------------------------------------------------------
// Pass B: per bucket, exclusive scan over the G=512 block counts.
// gbase[b][g] = base of block g within bucket b (coalesced write);
// bcnt[b] = total. 1563 blocks x 512 threads.
// ---------------------------------------------------------------------------
__global__ void __launch_bounds__(512) k_scanB(const u32* __restrict__ ghist,
                                               u32* __restrict__ gbase,
                                               u32* __restrict__ bcnt) {
    __shared__ u32 ps[G];
    int t = threadIdx.x;
    int b = blockIdx.x;
    u32 v = ghist[(size_t)t * NB + b];
    ps[t] = v;
    __syncthreads();
    for (int off = 1; off < G; off <<= 1) {
        u32 n = (t >= off) ? ps[t - off] : 0u;
        __syncthreads();
        ps[t] += n;
        __syncthreads();
    }
    gbase[(size_t)b * G + t] = ps[t] - v;      // exclusive
    if (t == G - 1) bcnt[b] = ps[t];
}

// ---------------------------------------------------------------------------
// Pass C: scatter into reserved per-(block,bucket) ranges. LDS cursors only.
// ---------------------------------------------------------------------------
__global__ void __launch_bounds__(256) k_scat(const int* __restrict__ ei,
                                              const u32* __restrict__ gbase,
                                              u32* __restrict__ binned,
                                              int cap) {
    __shared__ u32 cur[NB];
    int tid = threadIdx.x;
    int g = blockIdx.x;
    int e0 = g * CHUNK, e1 = min(e0 + CHUNK, N_EDGES);
    const int* dstp = ei + N_EDGES;
    for (int i = tid; i < NB; i += 256)
        cur[i] = gbase[(size_t)i * G + g];
    __syncthreads();
    for (int e = e0 + tid; e < e1; e += 256) {
        int d = dstp[e];
        int s = ei[e];
        int b = d >> BSH;
        u32 loc = atomicAdd(&cur[b], 1u);
        if (loc < (u32)cap)
            binned[(size_t)b * cap + loc] = ((u32)s << BSH) | (u32)(d & (BNODES - 1));
    }
}

// ---------------------------------------------------------------------------
// Fallback binning (small ws): LDS-privatized with global reservation atomics.
// ---------------------------------------------------------------------------
__global__ void __launch_bounds__(256) k_bin2(const int* __restrict__ ei,
                                              u32* __restrict__ bcnt,
                                              u32* __restrict__ binned,
                                              int cap) {
    __shared__ u32 hist[NB];
    __shared__ u32 rbase[NB];
    int tid = threadIdx.x;
    int e0 = blockIdx.x * BIN_CHUNK;
    int e1 = min(e0 + BIN_CHUNK, N_EDGES);
    const int* dstp = ei + N_EDGES;
    for (int i = tid; i < NB; i += 256) hist[i] = 0;
    __syncthreads();
    for (int e = e0 + tid; e < e1; e += 256)
        atomicAdd(&hist[dstp[e] >> BSH], 1u);
    __syncthreads();
    for (int i = tid; i < NB; i += 256) {
        u32 h = hist[i];
        rbase[i] = h ? atomicAdd(&bcnt[i], h) : 0u;
        hist[i] = 0;
    }
    __syncthreads();
    for (int e = e0 + tid; e < e1; e += 256) {
        int d = dstp[e];
        int s = ei[e];
        int b = d >> BSH;
        u32 loc = atomicAdd(&hist[b], 1u);
        u32 slot = rbase[b] + loc;
        if (slot < (u32)cap)
            binned[(size_t)b * cap + slot] = ((u32)s << BSH) | (u32)(d & (BNODES - 1));
    }
}

// ---------------------------------------------------------------------------
// Per-bucket counting sort, in place. Emits per-node absolute offsets + degree.
// ---------------------------------------------------------------------------
__global__ void __launch_bounds__(256) k_sort(u32* __restrict__ binned,
                                              const u32* __restrict__ bcnt,
                                              int cap,
                                              u32* __restrict__ offs,
                                              u32* __restrict__ deg) {
    __shared__ u32 eh[1024];
    __shared__ u32 hist[BNODES];
    __shared__ u32 cur[BNODES];
    int tid = threadIdx.x;
    int b = blockIdx.x;
    int cnt = min((int)bcnt[b], cap);
    u32* seg = binned + (size_t)b * cap;

    if (tid < BNODES) hist[tid] = 0;
    __syncthreads();
    for (int i = tid; i < cnt; i += 256) {
        u32 w = seg[i];
        eh[i] = w;
        atomicAdd(&hist[w & (BNODES - 1)], 1u);
    }
    __syncthreads();
    if (tid < BNODES) {
        u32 v = hist[tid];
        u32 s = v;
#pragma unroll
        for (int off = 1; off < 64; off <<= 1) {
            u32 n = __shfl_up(s, off, 64);
            if (tid >= off) s += n;
        }
        u32 excl = s - v;
        cur[tid] = excl;
        int node = (b << BSH) + tid;
        if (node < N_NODES) {
            offs[node] = (u32)((size_t)b * cap + excl);
            deg[node] = v;
        }
    }
    __syncthreads();
    for (int i = tid; i < cnt; i += 256) {
        u32 w = eh[i];
        u32 p = atomicAdd(&cur[w & (BNODES - 1)], 1u);
        seg[p] = w >> BSH;
    }
}

// ---------------------------------------------------------------------------
// Gather, bf16. One wave per node; QUARTER-wave per edge (16 lanes x uint2 =
// 4 features/lane), 16 edges per fully-masked pass -> no tail, 4 loads in
// flight. Mean degree 12.5 -> most nodes finish in one pass.
// ---------------------------------------------------------------------------
__global__ void __launch_bounds__(256) k_gather16(const u32* __restrict__ x16,
                                                  const u32* __restrict__ binned,
                                                  const u32* __restrict__ offs,
                                                  const u32* __restrict__ deg,
                                                  float* __restrict__ agg) {
    int tid = blockIdx.x * 256 + threadIdx.x;
    int node = tid >> 6;
    if (node >= N_NODES) return;
    int lane = threadIdx.x & 63;
    int sub = lane >> 4;          // edge slot 0..3
    int pr = lane & 15;           // feature quad 4pr..4pr+3
    const uint2* xv = (const uint2*)x16;
    u32 o0 = offs[node], dg = deg[node];
    u32 o1 = o0 + dg;
    float a0 = 0.f, a1 = 0.f, a2 = 0.f, a3 = 0.f;
    for (u32 j = o0; j < o1; j += 16) {
#pragma unroll
        for (int t = 0; t < 4; ++t) {
            u32 idxe = j + 4 * t + sub;
            bool ok = idxe < o1;
            u32 e = binned[ok ? idxe : o0];
            uint2 w = xv[(size_t)e * 16 + pr];
            float m = ok ? 1.f : 0.f;
            a0 += m * __uint_as_float(w.x << 16);
            a1 += m * __uint_as_float(w.x & 0xffff0000u);
            a2 += m * __uint_as_float(w.y << 16);
            a3 += m * __uint_as_float(w.y & 0xffff0000u);
        }
    }
    a0 += __shfl_xor(a0, 16); a1 += __shfl_xor(a1, 16);
    a2 += __shfl_xor(a2, 16); a3 += __shfl_xor(a3, 16);
    a0 += __shfl_xor(a0, 32); a1 += __shfl_xor(a1, 32);
    a2 += __shfl_xor(a2, 32); a3 += __shfl_xor(a3, 32);
    if (sub == 0) {
        float inv = 1.0f / (float)max(dg, 1u);
        *(float4*)&agg[(size_t)node * D + 4 * pr] =
            make_float4(a0 * inv, a1 * inv, a2 * inv, a3 * inv);
    }
}

// ---------------------------------------------------------------------------
// Gather fallback, fp32 x.
// ---------------------------------------------------------------------------
__global__ void __launch_bounds__(256) k_gather32(const float* __restrict__ x,
                                                  const u32* __restrict__ binned,
                                                  const u32* __restrict__ offs,
                                                  const u32* __restrict__ deg,
                                                  float* __restrict__ agg) {
    int tid = blockIdx.x * 256 + threadIdx.x;
    int node = tid >> 6;
    int d = tid & 63;
    if (node >= N_NODES) return;
    u32 o0 = offs[node], dg = deg[node];
    u32 o1 = o0 + dg;
    float s = 0.f;
    u32 j = o0;
    for (; j + 8 <= o1; j += 8) {
        u32 e[8];
        float v[8];
#pragma unroll
        for (int t = 0; t < 8; ++t) e[t] = binned[j + t];
#pragma unroll
        for (int t = 0; t < 8; ++t) v[t] = x[(size_t)e[t] * D + d];
#pragma unroll
        for (int t = 0; t < 8; ++t) s += v[t];
    }
    for (; j < o1; ++j) s += x[(size_t)binned[j] * D + d];
    agg[(size_t)node * D + d] = s / (float)max(dg, 1u);
}

// ---------------------------------------------------------------------------
// Transform GEMM, two K-halves sharing one A-tile buffer. float4 LDS staging.
// At[node][WSW] row-major; Wt[k][WSW] transposed. 52KB LDS -> 3 blocks/CU.
// ---------------------------------------------------------------------------
__global__ void __launch_bounds__(256) k_gemm(const float* __restrict__ x,
                                              const float* __restrict__ wn,
                                              const float* __restrict__ wsf,
                                              const float* __restrict__ bias,
                                              float* __restrict__ io) {
    __shared__ float At[BNODES * WSW];   // 17.4 KB
    __shared__ float Wt[128 * WSW];      // 34.8 KB
    int tid = threadIdx.x;
    int base = blockIdx.x * 64;

    const float4* iop = (const float4*)io;
    const float4* xp  = (const float4*)x;

    // Stage Wt transposed: Wt[k][d] = wn[d][k]; rows 64..127 = wsf.
    for (int i = tid; i < 4096; i += 256) {
        int d = i >> 6, k = i & 63;
        Wt[k * WSW + d] = wn[i];
        Wt[(64 + k) * WSW + d] = wsf[i];
    }
    // Stage At = agg rows (float4 writes).
    for (int i = tid; i < 1024; i += 256) {
        int r = i >> 4, q = i & 15;
        int node = base + r;
        float4 v = make_float4(0.f, 0.f, 0.f, 0.f);
        if (node < N_NODES) v = iop[(size_t)node * 16 + q];
        *(float4*)&At[r * WSW + q * 4] = v;
    }
    __syncthreads();

    int tn = tid >> 4, td = tid & 15;
    int n0 = tn * 4, d0 = td * 4;
    float4 b4 = *(const float4*)&bias[d0];
    float acc[4][4];
#pragma unroll
    for (int i = 0; i < 4; ++i) {
        acc[i][0] = b4.x; acc[i][1] = b4.y; acc[i][2] = b4.z; acc[i][3] = b4.w;
    }

    // Half-1: agg @ wn^T.
#pragma unroll 8
    for (int kc = 0; kc < 16; ++kc) {
        float4 a[4], w[4];
#pragma unroll
        for (int i = 0; i < 4; ++i) a[i] = *(const float4*)&At[(n0 + i) * WSW + kc * 4];
#pragma unroll
        for (int t = 0; t < 4; ++t) w[t] = *(const float4*)&Wt[(kc * 4 + t) * WSW + d0];
#pragma unroll
        for (int i = 0; i < 4; ++i) {
            const float av[4] = {a[i].x, a[i].y, a[i].z, a[i].w};
#pragma unroll
            for (int t = 0; t < 4; ++t) {
                acc[i][0] += av[t] * w[t].x;
                acc[i][1] += av[t] * w[t].y;
                acc[i][2] += av[t] * w[t].z;
                acc[i][3] += av[t] * w[t].w;
            }
        }
    }
    __syncthreads();

    // Restage At = x rows.
    for (int i = tid; i < 1024; i += 256) {
        int r = i >> 4, q = i & 15;
        int node = base + r;
        float4 v = make_float4(0.f, 0.f, 0.f, 0.f);
        if (node < N_NODES) v = xp[(size_t)node * 16 + q];
        *(float4*)&At[r * WSW + q * 4] = v;
    }
    __syncthreads();

    // Half-2: x @ ws^T.
#pragma unroll 8
    for (int kc = 0; kc < 16; ++kc) {
        float4 a[4], w[4];
#pragma unroll
        for (int i = 0; i < 4; ++i) a[i] = *(const float4*)&At[(n0 + i) * WSW + kc * 4];
#pragma unroll
        for (int t = 0; t < 4; ++t) w[t] = *(const float4*)&Wt[(64 + kc * 4 + t) * WSW + d0];
#pragma unroll
        for (int i = 0; i < 4; ++i) {
            const float av[4] = {a[i].x, a[i].y, a[i].z, a[i].w};
#pragma unroll
            for (int t = 0; t < 4; ++t) {
                acc[i][0] += av[t] * w[t].x;
                acc[i][1] += av[t] * w[t].y;
                acc[i][2] += av[t] * w[t].z;
                acc[i][3] += av[t] * w[t].w;
            }
        }
    }

#pragma unroll
    for (int i = 0; i < 4; ++i) {
        int node = base + n0 + i;
        if (node < N_NODES) {
            *(float4*)&io[(size_t)node * D + d0] =
                make_float4(acc[i][0], acc[i][1], acc[i][2], acc[i][3]);
        }
    }
}

extern "C" void kernel_launch(void* const* d_in, const int* in_sizes, int n_in,
                              void* d_out, int out_size, void* d_ws, size_t ws_size,
                              hipStream_t stream) {
    const float* x = (const float*)d_in[0];
    const int* ei = (const int*)d_in[1];
    const float* wn = (const float*)d_in[2];
    const float* wsf = (const float*)d_in[3];
    const float* bias = (const float*)d_in[4];
    float* out = (float*)d_out;

    // ws layout (u32): offs[100000] deg[100000] bcnt[pad16] [x16 3.2M] binned[NB*cap]
    u32* offs = (u32*)d_ws;
    u32* deg = offs + N_NODES;
    u32* bcnt = deg + N_NODES;
    u32* after_bcnt = bcnt + ((NB + 15) & ~15);
    size_t fixed = 2 * (size_t)N_NODES + ((NB + 15) & ~15);
    size_t avail = ws_size / 4 - fixed;
    const size_t X16W = (size_t)N_NODES * (D / 2);

    bool bf16 = false;
    int cap = 1024;
    u32 *x16 = nullptr, *binned = nullptr;
    if (avail >= X16W + (size_t)NB * 1024) {
        bf16 = true;
        x16 = after_bcnt;
        binned = x16 + X16W;
    } else {
        size_t capz = (avail / NB) & ~(size_t)3;
        cap = (int)(capz < 1024 ? capz : 1024);
        binned = after_bcnt;
    }

    if (bf16) {
        // Aliases (dead by the time their hosts are written):
        u32* ghist = binned;   // G*NB = 800,256 words <= NB*cap; dead before k_scat writes binned
        u32* gbase = x16;      // NB*G words <= X16W; dead before k_tobf16 writes x16
        k_hist<<<G, 256, 0, stream>>>(ei, ghist);
        k_scanB<<<NB, 512, 0, stream>>>(ghist, gbase, bcnt);
        k_scat<<<G, 256, 0, stream>>>(ei, gbase, binned, cap);
        k_tobf16<<<(N_NODES * D / 8 + 255) / 256, 256, 0, stream>>>(x, x16);
        k_sort<<<NB, 256, 0, stream>>>(binned, bcnt, cap, offs, deg);
        k_gather16<<<(N_NODES * 64) / 256, 256, 0, stream>>>(x16, binned, offs, deg, out);
    } else {
        hipMemsetAsync(bcnt, 0, ((NB + 15) & ~15) * sizeof(u32), stream);
        k_bin2<<<BIN_BLOCKS, 256, 0, stream>>>(ei, bcnt, binned, cap);
        k_sort<<<NB, 256, 0, stream>>>(binned, bcnt, cap, offs, deg);
        k_gather32<<<(N_NODES * 64) / 256, 256, 0, stream>>>(x, binned, offs, deg, out);
    }
    k_gemm<<<(N_NODES + 63) / 64, 256, 0, stream>>>(x, wn, wsf, bias, out);
}

// Round 8
// 131.400 us; speedup vs baseline: 4.3003x; 1.0318x over previous
//
#include <hip/hip_runtime.h>

#define N_NODES 100000
#define N_EDGES 1250000
#define D 64
#define BSH 6                  // 64 nodes per bucket
#define BNODES 64
#define NB 1563                // ceil(100000/64)
#define WSW 68                 // LDS row stride (floats), 272B = 16B-aligned
#define G 512                  // binning blocks
#define CHUNK ((N_EDGES + G - 1) / G)          // 2442
#define YZ_BN 128              // nodes per k_yz block
#define BIN_BLOCKS 128
#define BIN_CHUNK ((N_EDGES + BIN_BLOCKS - 1) / BIN_BLOCKS)

typedef unsigned int u32;

__device__ __forceinline__ u32 pack_bf16(float lo, float hi) {
    u32 a = __float_as_uint(lo);
    u32 b = __float_as_uint(hi);
    a = (a + 0x7fffu + ((a >> 16) & 1u)) >> 16;   // RNE
    b = (b + 0x7fffu + ((b >> 16) & 1u)) >> 16;
    return a | (b << 16);
}

// ---------------------------------------------------------------------------
// Pre-transpose both weight matrices into wtg[128][64]: rows 0..63 = Wn^T,
// rows 64..127 = Ws^T. Tiny (32KB), makes k_yz staging conflict-free both sides.
// ---------------------------------------------------------------------------
__global__ void __launch_bounds__(256) k_wprep(const float* __restrict__ wn,
                                               const float* __restrict__ wsf,
                                               float* __restrict__ wtg) {
    int i = blockIdx.x * 256 + threadIdx.x;   // 0..8191
    if (i >= 8192) return;
    int kk = i >> 6, d = i & 63;
    wtg[i] = (kk < 64) ? wn[d * 64 + kk] : wsf[d * 64 + (kk - 64)];
}

// ---------------------------------------------------------------------------
// Deterministic binning pass A: per-block LDS histogram -> ghist[g][b].
// ---------------------------------------------------------------------------
__global__ void __launch_bounds__(256) k_hist(const int* __restrict__ ei,
                                              u32* __restrict__ ghist) {
    __shared__ u32 hist[NB];
    int tid = threadIdx.x;
    int g = blockIdx.x;
    int e0 = g * CHUNK, e1 = min(e0 + CHUNK, N_EDGES);
    const int* dstp = ei + N_EDGES;
    for (int i = tid; i < NB; i += 256) hist[i] = 0;
    __syncthreads();
    for (int e = e0 + tid; e < e1; e += 256)
        atomicAdd(&hist[dstp[e] >> BSH], 1u);
    __syncthreads();
    for (int i = tid; i < NB; i += 256)
        ghist[(size_t)g * NB + i] = hist[i];
}

// ---------------------------------------------------------------------------
// Pass B: per-bucket exclusive scan over the G block counts; bcnt totals.
// ---------------------------------------------------------------------------
__global__ void __launch_bounds__(512) k_scanB(const u32* __restrict__ ghist,
                                               u32* __restrict__ gbase,
                                               u32* __restrict__ bcnt) {
    __shared__ u32 ps[G];
    int t = threadIdx.x;
    int b = blockIdx.x;
    u32 v = ghist[(size_t)t * NB + b];
    ps[t] = v;
    __syncthreads();
    for (int off = 1; off < G; off <<= 1) {
        u32 n = (t >= off) ? ps[t - off] : 0u;
        __syncthreads();
        ps[t] += n;
        __syncthreads();
    }
    gbase[(size_t)b * G + t] = ps[t] - v;
    if (t == G - 1) bcnt[b] = ps[t];
}

// ---------------------------------------------------------------------------
// Pass C: scatter into reserved per-(block,bucket) ranges. LDS cursors only.
// ---------------------------------------------------------------------------
__global__ void __launch_bounds__(256) k_scat(const int* __restrict__ ei,
                                              const u32* __restrict__ gbase,
                                              u32* __restrict__ binned,
                                              int cap) {
    __shared__ u32 cur[NB];
    int tid = threadIdx.x;
    int g = blockIdx.x;
    int e0 = g * CHUNK, e1 = min(e0 + CHUNK, N_EDGES);
    const int* dstp = ei + N_EDGES;
    for (int i = tid; i < NB; i += 256)
        cur[i] = gbase[(size_t)i * G + g];
    __syncthreads();
    for (int e = e0 + tid; e < e1; e += 256) {
        int d = dstp[e];
        int s = ei[e];
        int b = d >> BSH;
        u32 loc = atomicAdd(&cur[b], 1u);
        if (loc < (u32)cap)
            binned[(size_t)b * cap + loc] = ((u32)s << BSH) | (u32)(d & (BNODES - 1));
    }
}

// ---------------------------------------------------------------------------
// Y = x@Wn^T (bf16 out), Z = x@Ws^T + b (fp32, into d_out).
// 128-node tile, 256 thr, micro-tile 8 nodes x (4 Yd + 4 Zd) = 1.0 FMA/LDS-byte.
// K-rotation kk=(kc+tn)&15 de-conflicts At reads across the 4 lane-groups.
// ---------------------------------------------------------------------------
__global__ void __launch_bounds__(256) k_yz(const float* __restrict__ x,
                                            const float* __restrict__ wtg,
                                            const float* __restrict__ bias,
                                            u32* __restrict__ y16,
                                            float* __restrict__ zout) {
    __shared__ float At[YZ_BN * WSW];   // 34.8 KB
    __shared__ float Wt[128 * WSW];     // 34.8 KB
    int tid = threadIdx.x;
    int base = blockIdx.x * YZ_BN;

    const float4* wtg4 = (const float4*)wtg;
    for (int j = tid; j < 2048; j += 256) {
        int k = j >> 4, q = j & 15;
        *(float4*)&Wt[k * WSW + q * 4] = wtg4[j];
    }
    const float4* xp = (const float4*)x;
    for (int j = tid; j < 2048; j += 256) {
        int r = j >> 4, q = j & 15;
        int node = base + r;
        float4 v = make_float4(0.f, 0.f, 0.f, 0.f);
        if (node < N_NODES) v = xp[(size_t)node * 16 + q];
        *(float4*)&At[r * WSW + q * 4] = v;
    }
    __syncthreads();

    int tn = tid >> 4, td = tid & 15;
    int n0 = tn * 8, d0 = td * 4;
    float4 b4 = *(const float4*)&bias[d0];
    float ay[8][4], az[8][4];
#pragma unroll
    for (int i = 0; i < 8; ++i) {
        ay[i][0] = 0.f; ay[i][1] = 0.f; ay[i][2] = 0.f; ay[i][3] = 0.f;
        az[i][0] = b4.x; az[i][1] = b4.y; az[i][2] = b4.z; az[i][3] = b4.w;
    }

    for (int kc = 0; kc < 16; ++kc) {
        int kk = (kc + tn) & 15;
        float4 wn4[4], ws4[4];
#pragma unroll
        for (int t = 0; t < 4; ++t) {
            wn4[t] = *(const float4*)&Wt[(kk * 4 + t) * WSW + d0];
            ws4[t] = *(const float4*)&Wt[(64 + kk * 4 + t) * WSW + d0];
        }
#pragma unroll
        for (int i = 0; i < 8; ++i) {
            float4 a = *(const float4*)&At[(n0 + i) * WSW + kk * 4];
            float av[4] = {a.x, a.y, a.z, a.w};
#pragma unroll
            for (int t = 0; t < 4; ++t) {
                ay[i][0] += av[t] * wn4[t].x; ay[i][1] += av[t] * wn4[t].y;
                ay[i][2] += av[t] * wn4[t].z; ay[i][3] += av[t] * wn4[t].w;
                az[i][0] += av[t] * ws4[t].x; az[i][1] += av[t] * ws4[t].y;
                az[i][2] += av[t] * ws4[t].z; az[i][3] += av[t] * ws4[t].w;
            }
        }
    }

    uint2* yv = (uint2*)y16;
#pragma unroll
    for (int i = 0; i < 8; ++i) {
        int node = base + n0 + i;
        if (node < N_NODES) {
            yv[(size_t)node * 16 + td] =
                make_uint2(pack_bf16(ay[i][0], ay[i][1]), pack_bf16(ay[i][2], ay[i][3]));
            *(float4*)&zout[(size_t)node * D + d0] =
                make_float4(az[i][0], az[i][1], az[i][2], az[i][3]);
        }
    }
}

// ---------------------------------------------------------------------------
// Per-bucket counting sort, in place. Emits per-node absolute offsets + degree.
// ---------------------------------------------------------------------------
__global__ void __launch_bounds__(256) k_sort(u32* __restrict__ binned,
                                              const u32* __restrict__ bcnt,
                                              int cap,
                                              u32* __restrict__ offs,
                                              u32* __restrict__ deg) {
    __shared__ u32 eh[1024];
    __shared__ u32 hist[BNODES];
    __shared__ u32 cur[BNODES];
    int tid = threadIdx.x;
    int b = blockIdx.x;
    int cnt = min((int)bcnt[b], cap);
    u32* seg = binned + (size_t)b * cap;

    if (tid < BNODES) hist[tid] = 0;
    __syncthreads();
    for (int i = tid; i < cnt; i += 256) {
        u32 w = seg[i];
        eh[i] = w;
        atomicAdd(&hist[w & (BNODES - 1)], 1u);
    }
    __syncthreads();
    if (tid < BNODES) {
        u32 v = hist[tid];
        u32 s = v;
#pragma unroll
        for (int off = 1; off < 64; off <<= 1) {
            u32 n = __shfl_up(s, off, 64);
            if (tid >= off) s += n;
        }
        u32 excl = s - v;
        cur[tid] = excl;
        int node = (b << BSH) + tid;
        if (node < N_NODES) {
            offs[node] = (u32)((size_t)b * cap + excl);
            deg[node] = v;
        }
    }
    __syncthreads();
    for (int i = tid; i < cnt; i += 256) {
        u32 w = eh[i];
        u32 p = atomicAdd(&cur[w & (BNODES - 1)], 1u);
        seg[p] = w >> BSH;
    }
}

// ---------------------------------------------------------------------------
// Final gather: out[n] = Z[n] + mean(Y16[src]). One wave/node, quarter-wave
// per edge (16 lanes x uint2 = 4 bf16). Tail is exec-mask predicated
// (condition uniform per 16-lane group) -> no wasted dummy loads.
// ---------------------------------------------------------------------------
__global__ void __launch_bounds__(256) k_gather_yz(const u32* __restrict__ y16,
                                                   const u32* __restrict__ binned,
                                                   const u32* __restrict__ offs,
                                                   const u32* __restrict__ deg,
                                                   float* __restrict__ io) {
    int tid = blockIdx.x * 256 + threadIdx.x;
    int node = tid >> 6;
    if (node >= N_NODES) return;
    int lane = threadIdx.x & 63;
    int sub = lane >> 4;
    int pr = lane & 15;
    const uint2* yv = (const uint2*)y16;
    u32 o0 = offs[node], dg = deg[node];
    u32 o1 = o0 + dg;
    float a0 = 0.f, a1 = 0.f, a2 = 0.f, a3 = 0.f;
    u32 j = o0;
    for (; j + 16 <= o1; j += 16) {        // full pass, unmasked, 4 loads in flight
        u32 e[4];
        uint2 w[4];
#pragma unroll
        for (int t = 0; t < 4; ++t) e[t] = binned[j + 4 * t + sub];
#pragma unroll
        for (int t = 0; t < 4; ++t) w[t] = yv[(size_t)e[t] * 16 + pr];
#pragma unroll
        for (int t = 0; t < 4; ++t) {
            a0 += __uint_as_float(w[t].x << 16);
            a1 += __uint_as_float(w[t].x & 0xffff0000u);
            a2 += __uint_as_float(w[t].y << 16);
            a3 += __uint_as_float(w[t].y & 0xffff0000u);
        }
    }
#pragma unroll
    for (int t = 0; t < 4; ++t) {          // masked tail (<=1 pass)
        u32 idxe = j + 4 * t + sub;
        if (idxe < o1) {
            u32 e = binned[idxe];
            uint2 w = yv[(size_t)e * 16 + pr];
            a0 += __uint_as_float(w.x << 16);
            a1 += __uint_as_float(w.x & 0xffff0000u);
            a2 += __uint_as_float(w.y << 16);
            a3 += __uint_as_float(w.y & 0xffff0000u);
        }
    }
    a0 += __shfl_xor(a0, 16); a1 += __shfl_xor(a1, 16);
    a2 += __shfl_xor(a2, 16); a3 += __shfl_xor(a3, 16);
    a0 += __shfl_xor(a0, 32); a1 += __shfl_xor(a1, 32);
    a2 += __shfl_xor(a2, 32); a3 += __shfl_xor(a3, 32);
    if (sub == 0) {
        float inv = 1.0f / (float)max(dg, 1u);
        float4 z = *(const float4*)&io[(size_t)node * D + 4 * pr];
        *(float4*)&io[(size_t)node * D + 4 * pr] =
            make_float4(z.x + a0 * inv, z.y + a1 * inv, z.z + a2 * inv, z.w + a3 * inv);
    }
}

// ======================= fallback path (small workspace) ====================
__global__ void __launch_bounds__(256) k_bin2(const int* __restrict__ ei,
                                              u32* __restrict__ bcnt,
                                              u32* __restrict__ binned,
                                              int cap) {
    __shared__ u32 hist[NB];
    __shared__ u32 rbase[NB];
    int tid = threadIdx.x;
    int e0 = blockIdx.x * BIN_CHUNK;
    int e1 = min(e0 + BIN_CHUNK, N_EDGES);
    const int* dstp = ei + N_EDGES;
    for (int i = tid; i < NB; i += 256) hist[i] = 0;
    __syncthreads();
    for (int e = e0 + tid; e < e1; e += 256)
        atomicAdd(&hist[dstp[e] >> BSH], 1u);
    __syncthreads();
    for (int i = tid; i < NB; i += 256) {
        u32 h = hist[i];
        rbase[i] = h ? atomicAdd(&bcnt[i], h) : 0u;
        hist[i] = 0;
    }
    __syncthreads();
    for (int e = e0 + tid; e < e1; e += 256) {
        int d = dstp[e];
        int s = ei[e];
        int b = d >> BSH;
        u32 loc = atomicAdd(&hist[b], 1u);
        u32 slot = rbase[b] + loc;
        if (slot < (u32)cap)
            binned[(size_t)b * cap + slot] = ((u32)s << BSH) | (u32)(d & (BNODES - 1));
    }
}

__global__ void __launch_bounds__(256) k_gather32(const float* __restrict__ x,
                                                  const u32* __restrict__ binned,
                                                  const u32* __restrict__ offs,
                                                  const u32* __restrict__ deg,
                                                  float* __restrict__ agg) {
    int tid = blockIdx.x * 256 + threadIdx.x;
    int node = tid >> 6;
    int d = tid & 63;
    if (node >= N_NODES) return;
    u32 o0 = offs[node], dg = deg[node];
    u32 o1 = o0 + dg;
    float s = 0.f;
    u32 j = o0;
    for (; j + 8 <= o1; j += 8) {
        u32 e[8];
        float v[8];
#pragma unroll
        for (int t = 0; t < 8; ++t) e[t] = binned[j + t];
#pragma unroll
        for (int t = 0; t < 8; ++t) v[t] = x[(size_t)e[t] * D + d];
#pragma unroll
        for (int t = 0; t < 8; ++t) s += v[t];
    }
    for (; j < o1; ++j) s += x[(size_t)binned[j] * D + d];
    agg[(size_t)node * D + d] = s / (float)max(dg, 1u);
}

__global__ void __launch_bounds__(256) k_gemm_fb(const float* __restrict__ x,
                                                 const float* __restrict__ wn,
                                                 const float* __restrict__ wsf,
                                                 const float* __restrict__ bias,
                                                 float* __restrict__ io) {
    __shared__ float At[BNODES * WSW];
    __shared__ float Wt[128 * WSW];
    int tid = threadIdx.x;
    int base = blockIdx.x * 64;
    const float4* iop = (const float4*)io;
    const float4* xp  = (const float4*)x;
    for (int i = tid; i < 4096; i += 256) {
        int d = i >> 6, k = i & 63;
        Wt[k * WSW + d] = wn[i];
        Wt[(64 + k) * WSW + d] = wsf[i];
    }
    for (int i = tid; i < 1024; i += 256) {
        int r = i >> 4, q = i & 15;
        int node = base + r;
        float4 v = make_float4(0.f, 0.f, 0.f, 0.f);
        if (node < N_NODES) v = iop[(size_t)node * 16 + q];
        *(float4*)&At[r * WSW + q * 4] = v;
    }
    __syncthreads();
    int tn = tid >> 4, td = tid & 15;
    int n0 = tn * 4, d0 = td * 4;
    float4 b4 = *(const float4*)&bias[d0];
    float acc[4][4];
#pragma unroll
    for (int i = 0; i < 4; ++i) {
        acc[i][0] = b4.x; acc[i][1] = b4.y; acc[i][2] = b4.z; acc[i][3] = b4.w;
    }
#pragma unroll 8
    for (int kc = 0; kc < 16; ++kc) {
        float4 a[4], w[4];
#pragma unroll
        for (int i = 0; i < 4; ++i) a[i] = *(const float4*)&At[(n0 + i) * WSW + kc * 4];
#pragma unroll
        for (int t = 0; t < 4; ++t) w[t] = *(const float4*)&Wt[(kc * 4 + t) * WSW + d0];
#pragma unroll
        for (int i = 0; i < 4; ++i) {
            const float av[4] = {a[i].x, a[i].y, a[i].z, a[i].w};
#pragma unroll
            for (int t = 0; t < 4; ++t) {
                acc[i][0] += av[t] * w[t].x; acc[i][1] += av[t] * w[t].y;
                acc[i][2] += av[t] * w[t].z; acc[i][3] += av[t] * w[t].w;
            }
        }
    }
    __syncthreads();
    for (int i = tid; i < 1024; i += 256) {
        int r = i >> 4, q = i & 15;
        int node = base + r;
        float4 v = make_float4(0.f, 0.f, 0.f, 0.f);
        if (node < N_NODES) v = xp[(size_t)node * 16 + q];
        *(float4*)&At[r * WSW + q * 4] = v;
    }
    __syncthreads();
#pragma unroll 8
    for (int kc = 0; kc < 16; ++kc) {
        float4 a[4], w[4];
#pragma unroll
        for (int i = 0; i < 4; ++i) a[i] = *(const float4*)&At[(n0 + i) * WSW + kc * 4];
#pragma unroll
        for (int t = 0; t < 4; ++t) w[t] = *(const float4*)&Wt[(64 + kc * 4 + t) * WSW + d0];
#pragma unroll
        for (int i = 0; i < 4; ++i) {
            const float av[4] = {a[i].x, a[i].y, a[i].z, a[i].w};
#pragma unroll
            for (int t = 0; t < 4; ++t) {
                acc[i][0] += av[t] * w[t].x; acc[i][1] += av[t] * w[t].y;
                acc[i][2] += av[t] * w[t].z; acc[i][3] += av[t] * w[t].w;
            }
        }
    }
#pragma unroll
    for (int i = 0; i < 4; ++i) {
        int node = base + n0 + i;
        if (node < N_NODES) {
            *(float4*)&io[(size_t)node * D + d0] =
                make_float4(acc[i][0], acc[i][1], acc[i][2], acc[i][3]);
        }
    }
}

extern "C" void kernel_launch(void* const* d_in, const int* in_sizes, int n_in,
                              void* d_out, int out_size, void* d_ws, size_t ws_size,
                              hipStream_t stream) {
    const float* x = (const float*)d_in[0];
    const int* ei = (const int*)d_in[1];
    const float* wn = (const float*)d_in[2];
    const float* wsf = (const float*)d_in[3];
    const float* bias = (const float*)d_in[4];
    float* out = (float*)d_out;

    // ws layout (u32): offs[100000] deg[100000] bcnt[1568] wtg[8192] y16[3.2M] binned[NB*cap]
    u32* offs = (u32*)d_ws;
    u32* deg = offs + N_NODES;
    u32* bcnt = deg + N_NODES;
    u32* wtg = bcnt + ((NB + 15) & ~15);
    u32* y16 = wtg + 8192;
    const size_t Y16W = (size_t)N_NODES * (D / 2);   // 3.2M words
    u32* binned = y16 + Y16W;
    size_t fixed = 2 * (size_t)N_NODES + ((NB + 15) & ~15) + 8192;

    if (ws_size / 4 >= fixed + Y16W + (size_t)NB * 1024) {
        const int cap = 1024;
        // Aliases (dead before their hosts are written):
        u32* ghist = binned;   // G*NB = 800K words <= NB*cap; dead before k_scat writes binned
        u32* gbase = y16;      // NB*G = 800K words <= Y16W; dead before k_yz writes y16
        k_wprep<<<32, 256, 0, stream>>>(wn, wsf, (float*)wtg);
        k_hist<<<G, 256, 0, stream>>>(ei, ghist);
        k_scanB<<<NB, 512, 0, stream>>>(ghist, gbase, bcnt);
        k_scat<<<G, 256, 0, stream>>>(ei, gbase, binned, cap);
        k_yz<<<(N_NODES + YZ_BN - 1) / YZ_BN, 256, 0, stream>>>(x, (const float*)wtg, bias, y16, out);
        k_sort<<<NB, 256, 0, stream>>>(binned, bcnt, cap, offs, deg);
        k_gather_yz<<<(N_NODES * 64) / 256, 256, 0, stream>>>(y16, binned, offs, deg, out);
    } else {
        // Fallback: fp32 path, binned right after fixed region.
        binned = wtg;   // reuse
        size_t avail = ws_size / 4 - (fixed - 8192);
        size_t capz = (avail / NB) & ~(size_t)3;
        int cap = (int)(capz < 1024 ? capz : 1024);
        hipMemsetAsync(bcnt, 0, ((NB + 15) & ~15) * sizeof(u32), stream);
        k_bin2<<<BIN_BLOCKS, 256, 0, stream>>>(ei, bcnt, binned, cap);
        k_sort<<<NB, 256, 0, stream>>>(binned, bcnt, cap, offs, deg);
        k_gather32<<<(N_NODES * 64) / 256, 256, 0, stream>>>(x, binned, offs, deg, out);
        k_gemm_fb<<<(N_NODES + 63) / 64, 256, 0, stream>>>(x, wn, wsf, bias, out);
    }
}

// Round 9
// 121.027 us; speedup vs baseline: 4.6689x; 1.0857x over previous
//
#include <hip/hip_runtime.h>

#define N_NODES 100000
#define N_EDGES 1250000
#define D 64
#define BSH 6                  // 64 nodes per bucket
#define BNODES 64
#define NB 1563                // ceil(100000/64)
#define WSW 68                 // LDS row stride (floats), 272B = 16B-aligned
#define G 512                  // binning blocks / scanB width
#define CHUNK 2444             // per-block edge chunk, 4-aligned (512*2444 >= 1.25M)
#define YZ_BN 128              // nodes per k_yz block
#define BIN_BLOCKS 128
#define BIN_CHUNK ((N_EDGES + BIN_BLOCKS - 1) / BIN_BLOCKS)

typedef unsigned int u32;

__device__ __forceinline__ u32 pack_bf16(float lo, float hi) {
    u32 a = __float_as_uint(lo);
    u32 b = __float_as_uint(hi);
    a = (a + 0x7fffu + ((a >> 16) & 1u)) >> 16;   // RNE
    b = (b + 0x7fffu + ((b >> 16) & 1u)) >> 16;
    return a | (b << 16);
}

// ---------------------------------------------------------------------------
// Pre-transpose weights into wtg[128][64]: rows 0..63 = Wn^T, 64..127 = Ws^T.
// ---------------------------------------------------------------------------
__global__ void __launch_bounds__(256) k_wprep(const float* __restrict__ wn,
                                               const float* __restrict__ wsf,
                                               float* __restrict__ wtg) {
    int i = blockIdx.x * 256 + threadIdx.x;
    if (i >= 8192) return;
    int kk = i >> 6, d = i & 63;
    wtg[i] = (kk < 64) ? wn[d * 64 + kk] : wsf[d * 64 + (kk - 64)];
}

// ---------------------------------------------------------------------------
// Binning pass A: per-block LDS histogram -> ghist[b][g] (transposed layout
// so pass B reads coalesced). int4 edge reads (CHUNK 16B-aligned).
// ---------------------------------------------------------------------------
__global__ void __launch_bounds__(256) k_hist(const int* __restrict__ ei,
                                              u32* __restrict__ ghist) {
    __shared__ u32 hist[NB];
    int tid = threadIdx.x;
    int g = blockIdx.x;
    int e0 = g * CHUNK, e1 = min(e0 + CHUNK, N_EDGES);
    for (int i = tid; i < NB; i += 256) hist[i] = 0;
    __syncthreads();
    const int4* dp = (const int4*)(ei + N_EDGES + e0);
    int nv = (e1 - e0) >> 2;                 // exact: chunk sizes are 4-multiples
    for (int i = tid; i < nv; i += 256) {
        int4 d4 = dp[i];
        atomicAdd(&hist[d4.x >> BSH], 1u);
        atomicAdd(&hist[d4.y >> BSH], 1u);
        atomicAdd(&hist[d4.z >> BSH], 1u);
        atomicAdd(&hist[d4.w >> BSH], 1u);
    }
    __syncthreads();
    for (int i = tid; i < NB; i += 256)
        ghist[(size_t)i * G + g] = hist[i];
}

// ---------------------------------------------------------------------------
// Pass B: per-bucket exclusive scan over G block counts (coalesced [b][g]
// reads/writes); bcnt[b] = total.
// ---------------------------------------------------------------------------
__global__ void __launch_bounds__(512) k_scanB(const u32* __restrict__ ghist,
                                               u32* __restrict__ gbase,
                                               u32* __restrict__ bcnt) {
    __shared__ u32 ps[G];
    int t = threadIdx.x;
    int b = blockIdx.x;
    u32 v = ghist[(size_t)b * G + t];
    ps[t] = v;
    __syncthreads();
    for (int off = 1; off < G; off <<= 1) {
        u32 n = (t >= off) ? ps[t - off] : 0u;
        __syncthreads();
        ps[t] += n;
        __syncthreads();
    }
    gbase[(size_t)b * G + t] = ps[t] - v;
    if (t == G - 1) bcnt[b] = ps[t];
}

// ---------------------------------------------------------------------------
// Pass C: scatter into reserved per-(block,bucket) ranges. LDS cursors only.
// int4 edge reads.
// ---------------------------------------------------------------------------
__global__ void __launch_bounds__(256) k_scat(const int* __restrict__ ei,
                                              const u32* __restrict__ gbase,
                                              u32* __restrict__ binned,
                                              int cap) {
    __shared__ u32 cur[NB];
    int tid = threadIdx.x;
    int g = blockIdx.x;
    int e0 = g * CHUNK, e1 = min(e0 + CHUNK, N_EDGES);
    for (int i = tid; i < NB; i += 256)
        cur[i] = gbase[(size_t)i * G + g];
    __syncthreads();
    const int4* sp = (const int4*)(ei + e0);
    const int4* dp = (const int4*)(ei + N_EDGES + e0);
    int nv = (e1 - e0) >> 2;
    for (int i = tid; i < nv; i += 256) {
        int4 s4 = sp[i];
        int4 d4 = dp[i];
        int ss[4] = {s4.x, s4.y, s4.z, s4.w};
        int dd[4] = {d4.x, d4.y, d4.z, d4.w};
#pragma unroll
        for (int u = 0; u < 4; ++u) {
            int b = dd[u] >> BSH;
            u32 loc = atomicAdd(&cur[b], 1u);
            if (loc < (u32)cap)
                binned[(size_t)b * cap + loc] = ((u32)ss[u] << BSH) | (u32)(dd[u] & (BNODES - 1));
        }
    }
}

// ---------------------------------------------------------------------------
// Y = x@Wn^T (bf16 out), Z = x@Ws^T + b (fp32, into d_out). 128-node tile.
// ---------------------------------------------------------------------------
__global__ void __launch_bounds__(256) k_yz(const float* __restrict__ x,
                                            const float* __restrict__ wtg,
                                            const float* __restrict__ bias,
                                            u32* __restrict__ y16,
                                            float* __restrict__ zout) {
    __shared__ float At[YZ_BN * WSW];
    __shared__ float Wt[128 * WSW];
    int tid = threadIdx.x;
    int base = blockIdx.x * YZ_BN;

    const float4* wtg4 = (const float4*)wtg;
    for (int j = tid; j < 2048; j += 256) {
        int k = j >> 4, q = j & 15;
        *(float4*)&Wt[k * WSW + q * 4] = wtg4[j];
    }
    const float4* xp = (const float4*)x;
    for (int j = tid; j < 2048; j += 256) {
        int r = j >> 4, q = j & 15;
        int node = base + r;
        float4 v = make_float4(0.f, 0.f, 0.f, 0.f);
        if (node < N_NODES) v = xp[(size_t)node * 16 + q];
        *(float4*)&At[r * WSW + q * 4] = v;
    }
    __syncthreads();

    int tn = tid >> 4, td = tid & 15;
    int n0 = tn * 8, d0 = td * 4;
    float4 b4 = *(const float4*)&bias[d0];
    float ay[8][4], az[8][4];
#pragma unroll
    for (int i = 0; i < 8; ++i) {
        ay[i][0] = 0.f; ay[i][1] = 0.f; ay[i][2] = 0.f; ay[i][3] = 0.f;
        az[i][0] = b4.x; az[i][1] = b4.y; az[i][2] = b4.z; az[i][3] = b4.w;
    }

    for (int kc = 0; kc < 16; ++kc) {
        int kk = (kc + tn) & 15;
        float4 wn4[4], ws4[4];
#pragma unroll
        for (int t = 0; t < 4; ++t) {
            wn4[t] = *(const float4*)&Wt[(kk * 4 + t) * WSW + d0];
            ws4[t] = *(const float4*)&Wt[(64 + kk * 4 + t) * WSW + d0];
        }
#pragma unroll
        for (int i = 0; i < 8; ++i) {
            float4 a = *(const float4*)&At[(n0 + i) * WSW + kk * 4];
            float av[4] = {a.x, a.y, a.z, a.w};
#pragma unroll
            for (int t = 0; t < 4; ++t) {
                ay[i][0] += av[t] * wn4[t].x; ay[i][1] += av[t] * wn4[t].y;
                ay[i][2] += av[t] * wn4[t].z; ay[i][3] += av[t] * wn4[t].w;
                az[i][0] += av[t] * ws4[t].x; az[i][1] += av[t] * ws4[t].y;
                az[i][2] += av[t] * ws4[t].z; az[i][3] += av[t] * ws4[t].w;
            }
        }
    }

    uint2* yv = (uint2*)y16;
#pragma unroll
    for (int i = 0; i < 8; ++i) {
        int node = base + n0 + i;
        if (node < N_NODES) {
            yv[(size_t)node * 16 + td] =
                make_uint2(pack_bf16(ay[i][0], ay[i][1]), pack_bf16(ay[i][2], ay[i][3]));
            *(float4*)&zout[(size_t)node * D + d0] =
                make_float4(az[i][0], az[i][1], az[i][2], az[i][3]);
        }
    }
}

// ---------------------------------------------------------------------------
// Per-bucket counting sort, in place. Writes meta[node] = (abs offset, degree).
// uint4-vectorized segment reads.
// ---------------------------------------------------------------------------
__global__ void __launch_bounds__(256) k_sort(u32* __restrict__ binned,
                                              const u32* __restrict__ bcnt,
                                              int cap,
                                              uint2* __restrict__ meta) {
    __shared__ u32 eh[1024];
    __shared__ u32 hist[BNODES];
    __shared__ u32 cur[BNODES];
    int tid = threadIdx.x;
    int b = blockIdx.x;
    int cnt = min((int)bcnt[b], cap);
    u32* seg = binned + (size_t)b * cap;

    if (tid < BNODES) hist[tid] = 0;
    __syncthreads();
    const uint4* segv = (const uint4*)seg;
    int nv = cnt >> 2;
    for (int i = tid; i < nv; i += 256) {
        uint4 w4 = segv[i];
        *(uint4*)&eh[4 * i] = w4;
        atomicAdd(&hist[w4.x & (BNODES - 1)], 1u);
        atomicAdd(&hist[w4.y & (BNODES - 1)], 1u);
        atomicAdd(&hist[w4.z & (BNODES - 1)], 1u);
        atomicAdd(&hist[w4.w & (BNODES - 1)], 1u);
    }
    for (int i = (cnt & ~3) + tid; i < cnt; i += 256) {
        u32 w = seg[i];
        eh[i] = w;
        atomicAdd(&hist[w & (BNODES - 1)], 1u);
    }
    __syncthreads();
    if (tid < BNODES) {
        u32 v = hist[tid];
        u32 s = v;
#pragma unroll
        for (int off = 1; off < 64; off <<= 1) {
            u32 n = __shfl_up(s, off, 64);
            if (tid >= off) s += n;
        }
        u32 excl = s - v;
        cur[tid] = excl;
        int node = (b << BSH) + tid;
        if (node < N_NODES)
            meta[node] = make_uint2((u32)((size_t)b * cap + excl), v);
    }
    __syncthreads();
    for (int i = tid; i < cnt; i += 256) {
        u32 w = eh[i];
        u32 p = atomicAdd(&cur[w & (BNODES - 1)], 1u);
        seg[p] = w >> BSH;
    }
}

// ---------------------------------------------------------------------------
// Final gather: out[n] = Z[n] + mean(Y16[src]). One wave/node.
// ONE coalesced binned round (lane l loads index l, deg<=64), then indices
// distributed by __shfl (register exchange) -> all Y loads issue back-to-back:
// 8 in flight covering 32 edges/iter. Chain: meta -> binned -> yv = 3 rounds.
// deg>64 overflow handled by a (practically never taken) fallback loop.
// ---------------------------------------------------------------------------
__global__ void __launch_bounds__(256) k_gather_yz(const u32* __restrict__ y16,
                                                   const u32* __restrict__ binned,
                                                   const uint2* __restrict__ meta,
                                                   float* __restrict__ io) {
    int tid = blockIdx.x * 256 + threadIdx.x;
    int node = tid >> 6;
    if (node >= N_NODES) return;
    int lane = threadIdx.x & 63;
    int sub = lane >> 4;          // edge slot 0..3
    int pr = lane & 15;           // feature quad
    const uint2* yv = (const uint2*)y16;
    uint2 m = meta[node];
    u32 o0 = m.x, dg = m.y;

    u32 myidx = 0;
    if (lane < (int)dg) myidx = binned[o0 + lane];    // one coalesced round

    float a0 = 0.f, a1 = 0.f, a2 = 0.f, a3 = 0.f;
    u32 dmain = min(dg, 64u);
    for (u32 r = 0; r < dmain; r += 32) {
        uint2 w[8];
        float msk[8];
#pragma unroll
        for (int t = 0; t < 8; ++t) {
            u32 e = r + 4 * t + sub;                  // <= 63 always
            u32 idx = (u32)__shfl((int)myidx, (int)e);
            msk[t] = (e < dmain) ? 1.f : 0.f;
            w[t] = yv[(size_t)idx * 16 + pr];
        }
#pragma unroll
        for (int t = 0; t < 8; ++t) {
            a0 += msk[t] * __uint_as_float(w[t].x << 16);
            a1 += msk[t] * __uint_as_float(w[t].x & 0xffff0000u);
            a2 += msk[t] * __uint_as_float(w[t].y << 16);
            a3 += msk[t] * __uint_as_float(w[t].y & 0xffff0000u);
        }
    }
    // deg > 64 overflow (essentially never at mean degree 12.5)
    for (u32 j = o0 + 64; j < o0 + dg; j += 16) {
#pragma unroll
        for (int t = 0; t < 4; ++t) {
            u32 ie = j + 4 * t + sub;
            if (ie < o0 + dg) {
                u32 idx = binned[ie];
                uint2 w = yv[(size_t)idx * 16 + pr];
                a0 += __uint_as_float(w.x << 16);
                a1 += __uint_as_float(w.x & 0xffff0000u);
                a2 += __uint_as_float(w.y << 16);
                a3 += __uint_as_float(w.y & 0xffff0000u);
            }
        }
    }

    a0 += __shfl_xor(a0, 16); a1 += __shfl_xor(a1, 16);
    a2 += __shfl_xor(a2, 16); a3 += __shfl_xor(a3, 16);
    a0 += __shfl_xor(a0, 32); a1 += __shfl_xor(a1, 32);
    a2 += __shfl_xor(a2, 32); a3 += __shfl_xor(a3, 32);
    if (sub == 0) {
        float inv = 1.0f / (float)max(dg, 1u);
        float4 z = *(const float4*)&io[(size_t)node * D + 4 * pr];
        *(float4*)&io[(size_t)node * D + 4 * pr] =
            make_float4(z.x + a0 * inv, z.y + a1 * inv, z.z + a2 * inv, z.w + a3 * inv);
    }
}

// ======================= fallback path (small workspace) ====================
__global__ void __launch_bounds__(256) k_bin2(const int* __restrict__ ei,
                                              u32* __restrict__ bcnt,
                                              u32* __restrict__ binned,
                                              int cap) {
    __shared__ u32 hist[NB];
    __shared__ u32 rbase[NB];
    int tid = threadIdx.x;
    int e0 = blockIdx.x * BIN_CHUNK;
    int e1 = min(e0 + BIN_CHUNK, N_EDGES);
    const int* dstp = ei + N_EDGES;
    for (int i = tid; i < NB; i += 256) hist[i] = 0;
    __syncthreads();
    for (int e = e0 + tid; e < e1; e += 256)
        atomicAdd(&hist[dstp[e] >> BSH], 1u);
    __syncthreads();
    for (int i = tid; i < NB; i += 256) {
        u32 h = hist[i];
        rbase[i] = h ? atomicAdd(&bcnt[i], h) : 0u;
        hist[i] = 0;
    }
    __syncthreads();
    for (int e = e0 + tid; e < e1; e += 256) {
        int d = dstp[e];
        int s = ei[e];
        int b = d >> BSH;
        u32 loc = atomicAdd(&hist[b], 1u);
        u32 slot = rbase[b] + loc;
        if (slot < (u32)cap)
            binned[(size_t)b * cap + slot] = ((u32)s << BSH) | (u32)(d & (BNODES - 1));
    }
}

__global__ void __launch_bounds__(256) k_sort_fb(u32* __restrict__ binned,
                                                 const u32* __restrict__ bcnt,
                                                 int cap,
                                                 u32* __restrict__ offs,
                                                 u32* __restrict__ deg) {
    __shared__ u32 eh[1024];
    __shared__ u32 hist[BNODES];
    __shared__ u32 cur[BNODES];
    int tid = threadIdx.x;
    int b = blockIdx.x;
    int cnt = min((int)bcnt[b], cap);
    u32* seg = binned + (size_t)b * cap;
    if (tid < BNODES) hist[tid] = 0;
    __syncthreads();
    for (int i = tid; i < cnt; i += 256) {
        u32 w = seg[i];
        eh[i] = w;
        atomicAdd(&hist[w & (BNODES - 1)], 1u);
    }
    __syncthreads();
    if (tid < BNODES) {
        u32 v = hist[tid];
        u32 s = v;
#pragma unroll
        for (int off = 1; off < 64; off <<= 1) {
            u32 n = __shfl_up(s, off, 64);
            if (tid >= off) s += n;
        }
        u32 excl = s - v;
        cur[tid] = excl;
        int node = (b << BSH) + tid;
        if (node < N_NODES) {
            offs[node] = (u32)((size_t)b * cap + excl);
            deg[node] = v;
        }
    }
    __syncthreads();
    for (int i = tid; i < cnt; i += 256) {
        u32 w = eh[i];
        u32 p = atomicAdd(&cur[w & (BNODES - 1)], 1u);
        seg[p] = w >> BSH;
    }
}

__global__ void __launch_bounds__(256) k_gather32(const float* __restrict__ x,
                                                  const u32* __restrict__ binned,
                                                  const u32* __restrict__ offs,
                                                  const u32* __restrict__ deg,
                                                  float* __restrict__ agg) {
    int tid = blockIdx.x * 256 + threadIdx.x;
    int node = tid >> 6;
    int d = tid & 63;
    if (node >= N_NODES) return;
    u32 o0 = offs[node], dg = deg[node];
    u32 o1 = o0 + dg;
    float s = 0.f;
    u32 j = o0;
    for (; j + 8 <= o1; j += 8) {
        u32 e[8];
        float v[8];
#pragma unroll
        for (int t = 0; t < 8; ++t) e[t] = binned[j + t];
#pragma unroll
        for (int t = 0; t < 8; ++t) v[t] = x[(size_t)e[t] * D + d];
#pragma unroll
        for (int t = 0; t < 8; ++t) s += v[t];
    }
    for (; j < o1; ++j) s += x[(size_t)binned[j] * D + d];
    agg[(size_t)node * D + d] = s / (float)max(dg, 1u);
}

__global__ void __launch_bounds__(256) k_gemm_fb(const float* __restrict__ x,
                                                 const float* __restrict__ wn,
                                                 const float* __restrict__ wsf,
                                                 const float* __restrict__ bias,
                                                 float* __restrict__ io) {
    __shared__ float At[BNODES * WSW];
    __shared__ float Wt[128 * WSW];
    int tid = threadIdx.x;
    int base = blockIdx.x * 64;
    const float4* iop = (const float4*)io;
    const float4* xp  = (const float4*)x;
    for (int i = tid; i < 4096; i += 256) {
        int d = i >> 6, k = i & 63;
        Wt[k * WSW + d] = wn[i];
        Wt[(64 + k) * WSW + d] = wsf[i];
    }
    for (int i = tid; i < 1024; i += 256) {
        int r = i >> 4, q = i & 15;
        int node = base + r;
        float4 v = make_float4(0.f, 0.f, 0.f, 0.f);
        if (node < N_NODES) v = iop[(size_t)node * 16 + q];
        *(float4*)&At[r * WSW + q * 4] = v;
    }
    __syncthreads();
    int tn = tid >> 4, td = tid & 15;
    int n0 = tn * 4, d0 = td * 4;
    float4 b4 = *(const float4*)&bias[d0];
    float acc[4][4];
#pragma unroll
    for (int i = 0; i < 4; ++i) {
        acc[i][0] = b4.x; acc[i][1] = b4.y; acc[i][2] = b4.z; acc[i][3] = b4.w;
    }
#pragma unroll 8
    for (int kc = 0; kc < 16; ++kc) {
        float4 a[4], w[4];
#pragma unroll
        for (int i = 0; i < 4; ++i) a[i] = *(const float4*)&At[(n0 + i) * WSW + kc * 4];
#pragma unroll
        for (int t = 0; t < 4; ++t) w[t] = *(const float4*)&Wt[(kc * 4 + t) * WSW + d0];
#pragma unroll
        for (int i = 0; i < 4; ++i) {
            const float av[4] = {a[i].x, a[i].y, a[i].z, a[i].w};
#pragma unroll
            for (int t = 0; t < 4; ++t) {
                acc[i][0] += av[t] * w[t].x; acc[i][1] += av[t] * w[t].y;
                acc[i][2] += av[t] * w[t].z; acc[i][3] += av[t] * w[t].w;
            }
        }
    }
    __syncthreads();
    for (int i = tid; i < 1024; i += 256) {
        int r = i >> 4, q = i & 15;
        int node = base + r;
        float4 v = make_float4(0.f, 0.f, 0.f, 0.f);
        if (node < N_NODES) v = xp[(size_t)node * 16 + q];
        *(float4*)&At[r * WSW + q * 4] = v;
    }
    __syncthreads();
#pragma unroll 8
    for (int kc = 0; kc < 16; ++kc) {
        float4 a[4], w[4];
#pragma unroll
        for (int i = 0; i < 4; ++i) a[i] = *(const float4*)&At[(n0 + i) * WSW + kc * 4];
#pragma unroll
        for (int t = 0; t < 4; ++t) w[t] = *(const float4*)&Wt[(64 + kc * 4 + t) * WSW + d0];
#pragma unroll
        for (int i = 0; i < 4; ++i) {
            const float av[4] = {a[i].x, a[i].y, a[i].z, a[i].w};
#pragma unroll
            for (int t = 0; t < 4; ++t) {
                acc[i][0] += av[t] * w[t].x; acc[i][1] += av[t] * w[t].y;
                acc[i][2] += av[t] * w[t].z; acc[i][3] += av[t] * w[t].w;
            }
        }
    }
#pragma unroll
    for (int i = 0; i < 4; ++i) {
        int node = base + n0 + i;
        if (node < N_NODES) {
            *(float4*)&io[(size_t)node * D + d0] =
                make_float4(acc[i][0], acc[i][1], acc[i][2], acc[i][3]);
        }
    }
}

extern "C" void kernel_launch(void* const* d_in, const int* in_sizes, int n_in,
                              void* d_out, int out_size, void* d_ws, size_t ws_size,
                              hipStream_t stream) {
    const float* x = (const float*)d_in[0];
    const int* ei = (const int*)d_in[1];
    const float* wn = (const float*)d_in[2];
    const float* wsf = (const float*)d_in[3];
    const float* bias = (const float*)d_in[4];
    float* out = (float*)d_out;

    // ws layout (u32): meta[200000] bcnt[1568] wtg[8192] y16[3.2M] binned[NB*1024]
    u32* metaw = (u32*)d_ws;
    u32* bcnt = metaw + 2 * N_NODES;
    u32* wtg = bcnt + ((NB + 15) & ~15);
    u32* y16 = wtg + 8192;
    const size_t Y16W = (size_t)N_NODES * (D / 2);
    u32* binned = y16 + Y16W;
    size_t fixed = 2 * (size_t)N_NODES + ((NB + 15) & ~15) + 8192;

    if (ws_size / 4 >= fixed + Y16W + (size_t)NB * 1024) {
        const int cap = 1024;
        // Aliases (dead before their hosts are written):
        u32* ghist = binned;   // NB*G = 800K u32 <= NB*cap; dead before k_scat writes binned
        u32* gbase = y16;      // NB*G = 800K u32 <= Y16W; dead before k_yz writes y16
        k_wprep<<<32, 256, 0, stream>>>(wn, wsf, (float*)wtg);
        k_hist<<<G, 256, 0, stream>>>(ei, ghist);
        k_scanB<<<NB, 512, 0, stream>>>(ghist, gbase, bcnt);
        k_scat<<<G, 256, 0, stream>>>(ei, gbase, binned, cap);
        k_yz<<<(N_NODES + YZ_BN - 1) / YZ_BN, 256, 0, stream>>>(x, (const float*)wtg, bias, y16, out);
        k_sort<<<NB, 256, 0, stream>>>(binned, bcnt, cap, (uint2*)metaw);
        k_gather_yz<<<(N_NODES * 64) / 256, 256, 0, stream>>>(y16, binned, (const uint2*)metaw, out);
    } else {
        // Fallback: fp32 path.
        u32* offs = metaw;
        u32* deg = offs + N_NODES;
        binned = wtg;
        size_t avail = ws_size / 4 - (fixed - 8192);
        size_t capz = (avail / NB) & ~(size_t)3;
        int cap = (int)(capz < 1024 ? capz : 1024);
        hipMemsetAsync(bcnt, 0, ((NB + 15) & ~15) * sizeof(u32), stream);
        k_bin2<<<BIN_BLOCKS, 256, 0, stream>>>(ei, bcnt, binned, cap);
        k_sort_fb<<<NB, 256, 0, stream>>>(binned, bcnt, cap, offs, deg);
        k_gather32<<<(N_NODES * 64) / 256, 256, 0, stream>>>(x, binned, offs, deg, out);
        k_gemm_fb<<<(N_NODES + 63) / 64, 256, 0, stream>>>(x, wn, wsf, bias, out);
    }
}

// Round 10
// 103.868 us; speedup vs baseline: 5.4402x; 1.1652x over previous
//
#include <hip/hip_runtime.h>

#define N_NODES 100000
#define N_EDGES 1250000
#define D 64
#define BSH 6                  // 64 nodes per bucket
#define BNODES 64
#define NB 1563                // ceil(100000/64)
#define WSW 68                 // LDS row stride (floats) for fallback GEMM
#define G 512                  // binning blocks / scanB width
#define CHUNK 2444             // per-block edge chunk, 4-aligned
#define BIN_BLOCKS 128
#define BIN_CHUNK ((N_EDGES + BIN_BLOCKS - 1) / BIN_BLOCKS)

typedef unsigned int u32;
typedef short bf16x8 __attribute__((ext_vector_type(8)));   // 8 bf16 = 4 VGPRs
typedef float f32x4 __attribute__((ext_vector_type(4)));

__device__ __forceinline__ u32 pack_bf16(float lo, float hi) {
    u32 a = __float_as_uint(lo);
    u32 b = __float_as_uint(hi);
    a = (a + 0x7fffu + ((a >> 16) & 1u)) >> 16;   // RNE
    b = (b + 0x7fffu + ((b >> 16) & 1u)) >> 16;
    return a | (b << 16);
}

// ---------------------------------------------------------------------------
// Pack B = [Wn^T | Ws^T] (64k x 128n) into MFMA B-fragment layout, bf16:
// word i: t=i>>9 (N-tile), h=(i>>8)&1 (K-half), l=(i>>2)&63 (lane), q=i&3.
// lane l holds B[k = h*32 + (l>>4)*8 + j][n = t*16 + (l&15)], j=2q,2q+1.
// ---------------------------------------------------------------------------
__global__ void __launch_bounds__(256) k_wprep2(const float* __restrict__ wn,
                                                const float* __restrict__ wsf,
                                                u32* __restrict__ bfrag) {
    int i = blockIdx.x * 256 + threadIdx.x;
    if (i >= 4096) return;
    int t = i >> 9, h = (i >> 8) & 1, l = (i >> 2) & 63, q = i & 3;
    int k0 = h * 32 + (l >> 4) * 8 + 2 * q;
    int n = t * 16 + (l & 15);
    const float* w = (n < 64) ? &wn[(size_t)n * 64] : &wsf[(size_t)(n - 64) * 64];
    bfrag[i] = pack_bf16(w[k0], w[k0 + 1]);
}

// ---------------------------------------------------------------------------
// Binning pass A: per-block LDS histogram -> ghist[b][g] (coalesced for scanB).
// ---------------------------------------------------------------------------
__global__ void __launch_bounds__(256) k_hist(const int* __restrict__ ei,
                                              u32* __restrict__ ghist) {
    __shared__ u32 hist[NB];
    int tid = threadIdx.x;
    int g = blockIdx.x;
    int e0 = g * CHUNK, e1 = min(e0 + CHUNK, N_EDGES);
    for (int i = tid; i < NB; i += 256) hist[i] = 0;
    __syncthreads();
    const int4* dp = (const int4*)(ei + N_EDGES + e0);
    int nv = (e1 - e0) >> 2;
    for (int i = tid; i < nv; i += 256) {
        int4 d4 = dp[i];
        atomicAdd(&hist[d4.x >> BSH], 1u);
        atomicAdd(&hist[d4.y >> BSH], 1u);
        atomicAdd(&hist[d4.z >> BSH], 1u);
        atomicAdd(&hist[d4.w >> BSH], 1u);
    }
    __syncthreads();
    for (int i = tid; i < NB; i += 256)
        ghist[(size_t)i * G + g] = hist[i];
}

// ---------------------------------------------------------------------------
// Pass B: per-bucket exclusive scan over G block counts; bcnt[b] = total.
// ---------------------------------------------------------------------------
__global__ void __launch_bounds__(512) k_scanB(const u32* __restrict__ ghist,
                                               u32* __restrict__ gbase,
                                               u32* __restrict__ bcnt) {
    __shared__ u32 ps[G];
    int t = threadIdx.x;
    int b = blockIdx.x;
    u32 v = ghist[(size_t)b * G + t];
    ps[t] = v;
    __syncthreads();
    for (int off = 1; off < G; off <<= 1) {
        u32 n = (t >= off) ? ps[t - off] : 0u;
        __syncthreads();
        ps[t] += n;
        __syncthreads();
    }
    gbase[(size_t)b * G + t] = ps[t] - v;
    if (t == G - 1) bcnt[b] = ps[t];
}

// ---------------------------------------------------------------------------
// Pass C: scatter into reserved per-(block,bucket) ranges. LDS cursors only.
// ---------------------------------------------------------------------------
__global__ void __launch_bounds__(256) k_scat(const int* __restrict__ ei,
                                              const u32* __restrict__ gbase,
                                              u32* __restrict__ binned,
                                              int cap) {
    __shared__ u32 cur[NB];
    int tid = threadIdx.x;
    int g = blockIdx.x;
    int e0 = g * CHUNK, e1 = min(e0 + CHUNK, N_EDGES);
    for (int i = tid; i < NB; i += 256)
        cur[i] = gbase[(size_t)i * G + g];
    __syncthreads();
    const int4* sp = (const int4*)(ei + e0);
    const int4* dp = (const int4*)(ei + N_EDGES + e0);
    int nv = (e1 - e0) >> 2;
    for (int i = tid; i < nv; i += 256) {
        int4 s4 = sp[i];
        int4 d4 = dp[i];
        int ss[4] = {s4.x, s4.y, s4.z, s4.w};
        int dd[4] = {d4.x, d4.y, d4.z, d4.w};
#pragma unroll
        for (int u = 0; u < 4; ++u) {
            int b = dd[u] >> BSH;
            u32 loc = atomicAdd(&cur[b], 1u);
            if (loc < (u32)cap)
                binned[(size_t)b * cap + loc] = ((u32)ss[u] << BSH) | (u32)(dd[u] & (BNODES - 1));
        }
    }
}

// ---------------------------------------------------------------------------
// MFMA GEMM: [Y | Z] = bf16(x) @ B, Y bf16 packed to y16, Z fp32 + bias to
// d_out. Block = 4 waves x 32 nodes = 128 nodes. Per wave: 2 M-tiles x
// 8 N-tiles x K=64 -> 32 x mfma_f32_16x16x32_bf16. No LDS; B frags from a
// 16KB L2-hot prepacked buffer (chunked 4 N-tiles to bound VGPR).
// C/D layout (m89): col = lane&15, row = (lane>>4)*4 + reg.
// ---------------------------------------------------------------------------
__global__ void __launch_bounds__(256) k_mm(const float* __restrict__ x,
                                            const u32* __restrict__ bfrag,
                                            const float* __restrict__ bias,
                                            u32* __restrict__ y16,
                                            float* __restrict__ zout) {
    int tid = threadIdx.x;
    int w = tid >> 6, l = tid & 63;
    int lg = l >> 4, c = l & 15;
    int nodebase = blockIdx.x * 128 + w * 32;

    union FU { uint4 u; bf16x8 v; };

    // A fragments: 2 M-tiles x 2 K-halves, built inline from fp32 x.
    bf16x8 af[2][2];
#pragma unroll
    for (int m = 0; m < 2; ++m) {
        int node = nodebase + m * 16 + c;
        if (node >= N_NODES) node = N_NODES - 1;   // clamp; OOB rows never stored
        const float4* xr = (const float4*)(x + (size_t)node * D);
#pragma unroll
        for (int h = 0; h < 2; ++h) {
            float4 p0 = xr[h * 8 + lg * 2];
            float4 p1 = xr[h * 8 + lg * 2 + 1];
            FU au;
            au.u.x = pack_bf16(p0.x, p0.y);
            au.u.y = pack_bf16(p0.z, p0.w);
            au.u.z = pack_bf16(p1.x, p1.y);
            au.u.w = pack_bf16(p1.z, p1.w);
            af[m][h] = au.v;
        }
    }

    // Accumulators: tiles 0..3 = Y (init 0), tiles 4..7 = Z (init bias).
    f32x4 acc[2][8];
#pragma unroll
    for (int m = 0; m < 2; ++m) {
#pragma unroll
        for (int t = 0; t < 4; ++t) acc[m][t] = (f32x4){0.f, 0.f, 0.f, 0.f};
#pragma unroll
        for (int t = 4; t < 8; ++t) {
            float bb = bias[(t - 4) * 16 + c];
            acc[m][t] = (f32x4){bb, bb, bb, bb};
        }
    }

    const uint4* bp = (const uint4*)bfrag;
#pragma unroll
    for (int tc = 0; tc < 2; ++tc) {           // 4 N-tiles per chunk
        bf16x8 bf[4][2];
#pragma unroll
        for (int tt = 0; tt < 4; ++tt)
#pragma unroll
            for (int h = 0; h < 2; ++h) {
                FU bu;
                bu.u = bp[(((tc * 4 + tt) * 2 + h) * 64) + l];
                bf[tt][h] = bu.v;
            }
#pragma unroll
        for (int m = 0; m < 2; ++m)
#pragma unroll
            for (int tt = 0; tt < 4; ++tt) {
                int t = tc * 4 + tt;
                acc[m][t] = __builtin_amdgcn_mfma_f32_16x16x32_bf16(
                    af[m][0], bf[tt][0], acc[m][t], 0, 0, 0);
                acc[m][t] = __builtin_amdgcn_mfma_f32_16x16x32_bf16(
                    af[m][1], bf[tt][1], acc[m][t], 0, 0, 0);
            }
    }

    // Stores. Row of reg r = (l>>4)*4 + r.
#pragma unroll
    for (int m = 0; m < 2; ++m) {
        int rowbase = nodebase + m * 16 + lg * 4;
#pragma unroll
        for (int r = 0; r < 4; ++r) {
            int node = rowbase + r;
            bool ok = node < N_NODES;
#pragma unroll
            for (int t = 4; t < 8; ++t) {      // Z: fp32, quarter-wave 64B segs
                if (ok) zout[(size_t)node * D + (t - 4) * 16 + c] = acc[m][t][r];
            }
#pragma unroll
            for (int t = 0; t < 4; ++t) {      // Y: bf16 pair via shfl_xor(1)
                float v = acc[m][t][r];
                float o = __shfl_xor(v, 1);
                if (ok && !(c & 1))
                    y16[(size_t)node * 32 + t * 8 + (c >> 1)] = pack_bf16(v, o);
            }
        }
    }
}

// ---------------------------------------------------------------------------
// Per-bucket counting sort, in place. meta[node] = (abs offset, degree).
// ---------------------------------------------------------------------------
__global__ void __launch_bounds__(256) k_sort(u32* __restrict__ binned,
                                              const u32* __restrict__ bcnt,
                                              int cap,
                                              uint2* __restrict__ meta) {
    __shared__ u32 eh[1024];
    __shared__ u32 hist[BNODES];
    __shared__ u32 cur[BNODES];
    int tid = threadIdx.x;
    int b = blockIdx.x;
    int cnt = min((int)bcnt[b], cap);
    u32* seg = binned + (size_t)b * cap;

    if (tid < BNODES) hist[tid] = 0;
    __syncthreads();
    const uint4* segv = (const uint4*)seg;
    int nv = cnt >> 2;
    for (int i = tid; i < nv; i += 256) {
        uint4 w4 = segv[i];
        *(uint4*)&eh[4 * i] = w4;
        atomicAdd(&hist[w4.x & (BNODES - 1)], 1u);
        atomicAdd(&hist[w4.y & (BNODES - 1)], 1u);
        atomicAdd(&hist[w4.z & (BNODES - 1)], 1u);
        atomicAdd(&hist[w4.w & (BNODES - 1)], 1u);
    }
    for (int i = (cnt & ~3) + tid; i < cnt; i += 256) {
        u32 w = seg[i];
        eh[i] = w;
        atomicAdd(&hist[w & (BNODES - 1)], 1u);
    }
    __syncthreads();
    if (tid < BNODES) {
        u32 v = hist[tid];
        u32 s = v;
#pragma unroll
        for (int off = 1; off < 64; off <<= 1) {
            u32 n = __shfl_up(s, off, 64);
            if (tid >= off) s += n;
        }
        u32 excl = s - v;
        cur[tid] = excl;
        int node = (b << BSH) + tid;
        if (node < N_NODES)
            meta[node] = make_uint2((u32)((size_t)b * cap + excl), v);
    }
    __syncthreads();
    for (int i = tid; i < cnt; i += 256) {
        u32 w = eh[i];
        u32 p = atomicAdd(&cur[w & (BNODES - 1)], 1u);
        seg[p] = w >> BSH;
    }
}

// ---------------------------------------------------------------------------
// Final gather: out[n] = Z[n] + mean(Y16[src]). One wave/node; one coalesced
// binned round + __shfl index distribution; 8 Y loads in flight.
// ---------------------------------------------------------------------------
__global__ void __launch_bounds__(256) k_gather_yz(const u32* __restrict__ y16,
                                                   const u32* __restrict__ binned,
                                                   const uint2* __restrict__ meta,
                                                   float* __restrict__ io) {
    int tid = blockIdx.x * 256 + threadIdx.x;
    int node = tid >> 6;
    if (node >= N_NODES) return;
    int lane = threadIdx.x & 63;
    int sub = lane >> 4;
    int pr = lane & 15;
    const uint2* yv = (const uint2*)y16;
    uint2 m = meta[node];
    u32 o0 = m.x, dg = m.y;

    u32 myidx = 0;
    if (lane < (int)dg) myidx = binned[o0 + lane];

    float a0 = 0.f, a1 = 0.f, a2 = 0.f, a3 = 0.f;
    u32 dmain = min(dg, 64u);
    for (u32 r = 0; r < dmain; r += 32) {
        uint2 w[8];
        float msk[8];
#pragma unroll
        for (int t = 0; t < 8; ++t) {
            u32 e = r + 4 * t + sub;
            u32 idx = (u32)__shfl((int)myidx, (int)e);
            msk[t] = (e < dmain) ? 1.f : 0.f;
            w[t] = yv[(size_t)idx * 16 + pr];
        }
#pragma unroll
        for (int t = 0; t < 8; ++t) {
            a0 += msk[t] * __uint_as_float(w[t].x << 16);
            a1 += msk[t] * __uint_as_float(w[t].x & 0xffff0000u);
            a2 += msk[t] * __uint_as_float(w[t].y << 16);
            a3 += msk[t] * __uint_as_float(w[t].y & 0xffff0000u);
        }
    }
    for (u32 j = o0 + 64; j < o0 + dg; j += 16) {   // deg>64 overflow (rare)
#pragma unroll
        for (int t = 0; t < 4; ++t) {
            u32 ie = j + 4 * t + sub;
            if (ie < o0 + dg) {
                u32 idx = binned[ie];
                uint2 w = yv[(size_t)idx * 16 + pr];
                a0 += __uint_as_float(w.x << 16);
                a1 += __uint_as_float(w.x & 0xffff0000u);
                a2 += __uint_as_float(w.y << 16);
                a3 += __uint_as_float(w.y & 0xffff0000u);
            }
        }
    }

    a0 += __shfl_xor(a0, 16); a1 += __shfl_xor(a1, 16);
    a2 += __shfl_xor(a2, 16); a3 += __shfl_xor(a3, 16);
    a0 += __shfl_xor(a0, 32); a1 += __shfl_xor(a1, 32);
    a2 += __shfl_xor(a2, 32); a3 += __shfl_xor(a3, 32);
    if (sub == 0) {
        float inv = 1.0f / (float)max(dg, 1u);
        float4 z = *(const float4*)&io[(size_t)node * D + 4 * pr];
        *(float4*)&io[(size_t)node * D + 4 * pr] =
            make_float4(z.x + a0 * inv, z.y + a1 * inv, z.z + a2 * inv, z.w + a3 * inv);
    }
}

// ======================= fallback path (small workspace) ====================
__global__ void __launch_bounds__(256) k_bin2(const int* __restrict__ ei,
                                              u32* __restrict__ bcnt,
                                              u32* __restrict__ binned,
                                              int cap) {
    __shared__ u32 hist[NB];
    __shared__ u32 rbase[NB];
    int tid = threadIdx.x;
    int e0 = blockIdx.x * BIN_CHUNK;
    int e1 = min(e0 + BIN_CHUNK, N_EDGES);
    const int* dstp = ei + N_EDGES;
    for (int i = tid; i < NB; i += 256) hist[i] = 0;
    __syncthreads();
    for (int e = e0 + tid; e < e1; e += 256)
        atomicAdd(&hist[dstp[e] >> BSH], 1u);
    __syncthreads();
    for (int i = tid; i < NB; i += 256) {
        u32 h = hist[i];
        rbase[i] = h ? atomicAdd(&bcnt[i], h) : 0u;
        hist[i] = 0;
    }
    __syncthreads();
    for (int e = e0 + tid; e < e1; e += 256) {
        int d = dstp[e];
        int s = ei[e];
        int b = d >> BSH;
        u32 loc = atomicAdd(&hist[b], 1u);
        u32 slot = rbase[b] + loc;
        if (slot < (u32)cap)
            binned[(size_t)b * cap + slot] = ((u32)s << BSH) | (u32)(d & (BNODES - 1));
    }
}

__global__ void __launch_bounds__(256) k_sort_fb(u32* __restrict__ binned,
                                                 const u32* __restrict__ bcnt,
                                                 int cap,
                                                 u32* __restrict__ offs,
                                                 u32* __restrict__ deg) {
    __shared__ u32 eh[1024];
    __shared__ u32 hist[BNODES];
    __shared__ u32 cur[BNODES];
    int tid = threadIdx.x;
    int b = blockIdx.x;
    int cnt = min((int)bcnt[b], cap);
    u32* seg = binned + (size_t)b * cap;
    if (tid < BNODES) hist[tid] = 0;
    __syncthreads();
    for (int i = tid; i < cnt; i += 256) {
        u32 w = seg[i];
        eh[i] = w;
        atomicAdd(&hist[w & (BNODES - 1)], 1u);
    }
    __syncthreads();
    if (tid < BNODES) {
        u32 v = hist[tid];
        u32 s = v;
#pragma unroll
        for (int off = 1; off < 64; off <<= 1) {
            u32 n = __shfl_up(s, off, 64);
            if (tid >= off) s += n;
        }
        u32 excl = s - v;
        cur[tid] = excl;
        int node = (b << BSH) + tid;
        if (node < N_NODES) {
            offs[node] = (u32)((size_t)b * cap + excl);
            deg[node] = v;
        }
    }
    __syncthreads();
    for (int i = tid; i < cnt; i += 256) {
        u32 w = eh[i];
        u32 p = atomicAdd(&cur[w & (BNODES - 1)], 1u);
        seg[p] = w >> BSH;
    }
}

__global__ void __launch_bounds__(256) k_gather32(const float* __restrict__ x,
                                                  const u32* __restrict__ binned,
                                                  const u32* __restrict__ offs,
                                                  const u32* __restrict__ deg,
                                                  float* __restrict__ agg) {
    int tid = blockIdx.x * 256 + threadIdx.x;
    int node = tid >> 6;
    int d = tid & 63;
    if (node >= N_NODES) return;
    u32 o0 = offs[node], dg = deg[node];
    u32 o1 = o0 + dg;
    float s = 0.f;
    u32 j = o0;
    for (; j + 8 <= o1; j += 8) {
        u32 e[8];
        float v[8];
#pragma unroll
        for (int t = 0; t < 8; ++t) e[t] = binned[j + t];
#pragma unroll
        for (int t = 0; t < 8; ++t) v[t] = x[(size_t)e[t] * D + d];
#pragma unroll
        for (int t = 0; t < 8; ++t) s += v[t];
    }
    for (; j < o1; ++j) s += x[(size_t)binned[j] * D + d];
    agg[(size_t)node * D + d] = s / (float)max(dg, 1u);
}

__global__ void __launch_bounds__(256) k_gemm_fb(const float* __restrict__ x,
                                                 const float* __restrict__ wn,
                                                 const float* __restrict__ wsf,
                                                 const float* __restrict__ bias,
                                                 float* __restrict__ io) {
    __shared__ float At[BNODES * WSW];
    __shared__ float Wt[128 * WSW];
    int tid = threadIdx.x;
    int base = blockIdx.x * 64;
    const float4* iop = (const float4*)io;
    const float4* xp  = (const float4*)x;
    for (int i = tid; i < 4096; i += 256) {
        int d = i >> 6, k = i & 63;
        Wt[k * WSW + d] = wn[i];
        Wt[(64 + k) * WSW + d] = wsf[i];
    }
    for (int i = tid; i < 1024; i += 256) {
        int r = i >> 4, q = i & 15;
        int node = base + r;
        float4 v = make_float4(0.f, 0.f, 0.f, 0.f);
        if (node < N_NODES) v = iop[(size_t)node * 16 + q];
        *(float4*)&At[r * WSW + q * 4] = v;
    }
    __syncthreads();
    int tn = tid >> 4, td = tid & 15;
    int n0 = tn * 4, d0 = td * 4;
    float4 b4 = *(const float4*)&bias[d0];
    float acc[4][4];
#pragma unroll
    for (int i = 0; i < 4; ++i) {
        acc[i][0] = b4.x; acc[i][1] = b4.y; acc[i][2] = b4.z; acc[i][3] = b4.w;
    }
#pragma unroll 8
    for (int kc = 0; kc < 16; ++kc) {
        float4 a[4], w[4];
#pragma unroll
        for (int i = 0; i < 4; ++i) a[i] = *(const float4*)&At[(n0 + i) * WSW + kc * 4];
#pragma unroll
        for (int t = 0; t < 4; ++t) w[t] = *(const float4*)&Wt[(kc * 4 + t) * WSW + d0];
#pragma unroll
        for (int i = 0; i < 4; ++i) {
            const float av[4] = {a[i].x, a[i].y, a[i].z, a[i].w};
#pragma unroll
            for (int t = 0; t < 4; ++t) {
                acc[i][0] += av[t] * w[t].x; acc[i][1] += av[t] * w[t].y;
                acc[i][2] += av[t] * w[t].z; acc[i][3] += av[t] * w[t].w;
            }
        }
    }
    __syncthreads();
    for (int i = tid; i < 1024; i += 256) {
        int r = i >> 4, q = i & 15;
        int node = base + r;
        float4 v = make_float4(0.f, 0.f, 0.f, 0.f);
        if (node < N_NODES) v = xp[(size_t)node * 16 + q];
        *(float4*)&At[r * WSW + q * 4] = v;
    }
    __syncthreads();
#pragma unroll 8
    for (int kc = 0; kc < 16; ++kc) {
        float4 a[4], w[4];
#pragma unroll
        for (int i = 0; i < 4; ++i) a[i] = *(const float4*)&At[(n0 + i) * WSW + kc * 4];
#pragma unroll
        for (int t = 0; t < 4; ++t) w[t] = *(const float4*)&Wt[(64 + kc * 4 + t) * WSW + d0];
#pragma unroll
        for (int i = 0; i < 4; ++i) {
            const float av[4] = {a[i].x, a[i].y, a[i].z, a[i].w};
#pragma unroll
            for (int t = 0; t < 4; ++t) {
                acc[i][0] += av[t] * w[t].x; acc[i][1] += av[t] * w[t].y;
                acc[i][2] += av[t] * w[t].z; acc[i][3] += av[t] * w[t].w;
            }
        }
    }
#pragma unroll
    for (int i = 0; i < 4; ++i) {
        int node = base + n0 + i;
        if (node < N_NODES) {
            *(float4*)&io[(size_t)node * D + d0] =
                make_float4(acc[i][0], acc[i][1], acc[i][2], acc[i][3]);
        }
    }
}

extern "C" void kernel_launch(void* const* d_in, const int* in_sizes, int n_in,
                              void* d_out, int out_size, void* d_ws, size_t ws_size,
                              hipStream_t stream) {
    const float* x = (const float*)d_in[0];
    const int* ei = (const int*)d_in[1];
    const float* wn = (const float*)d_in[2];
    const float* wsf = (const float*)d_in[3];
    const float* bias = (const float*)d_in[4];
    float* out = (float*)d_out;

    // ws layout (u32): meta[200000] bcnt[1568] bfrag[8192] y16[3.2M] binned[NB*1024]
    u32* metaw = (u32*)d_ws;
    u32* bcnt = metaw + 2 * N_NODES;
    u32* bfrag = bcnt + ((NB + 15) & ~15);
    u32* y16 = bfrag + 8192;
    const size_t Y16W = (size_t)N_NODES * (D / 2);
    u32* binned = y16 + Y16W;
    size_t fixed = 2 * (size_t)N_NODES + ((NB + 15) & ~15) + 8192;

    if (ws_size / 4 >= fixed + Y16W + (size_t)NB * 1024) {
        const int cap = 1024;
        // Aliases (dead before their hosts are written):
        u32* ghist = binned;   // NB*G = 800K u32 <= NB*cap; dead before k_scat writes binned
        u32* gbase = y16;      // NB*G = 800K u32 <= Y16W;   dead before k_mm writes y16
        k_wprep2<<<16, 256, 0, stream>>>(wn, wsf, bfrag);
        k_hist<<<G, 256, 0, stream>>>(ei, ghist);
        k_scanB<<<NB, 512, 0, stream>>>(ghist, gbase, bcnt);
        k_scat<<<G, 256, 0, stream>>>(ei, gbase, binned, cap);
        k_mm<<<(N_NODES + 127) / 128, 256, 0, stream>>>(x, bfrag, bias, y16, out);
        k_sort<<<NB, 256, 0, stream>>>(binned, bcnt, cap, (uint2*)metaw);
        k_gather_yz<<<(N_NODES * 64) / 256, 256, 0, stream>>>(y16, binned, (const uint2*)metaw, out);
    } else {
        // Fallback: fp32 path.
        u32* offs = metaw;
        u32* deg = offs + N_NODES;
        binned = bfrag;
        size_t avail = ws_size / 4 - (fixed - 8192);
        size_t capz = (avail / NB) & ~(size_t)3;
        int cap = (int)(capz < 1024 ? capz : 1024);
        hipMemsetAsync(bcnt, 0, ((NB + 15) & ~15) * sizeof(u32), stream);
        k_bin2<<<BIN_BLOCKS, 256, 0, stream>>>(ei, bcnt, binned, cap);
        k_sort_fb<<<NB, 256, 0, stream>>>(binned, bcnt, cap, offs, deg);
        k_gather32<<<(N_NODES * 64) / 256, 256, 0, stream>>>(x, binned, offs, deg, out);
        k_gemm_fb<<<(N_NODES + 63) / 64, 256, 0, stream>>>(x, wn, wsf, bias, out);
    }
}

// Round 11
// 100.297 us; speedup vs baseline: 5.6339x; 1.0356x over previous
//
#include <hip/hip_runtime.h>

#define N_NODES 100000
#define N_EDGES 1250000
#define D 64
#define BSH 6                  // 64 nodes per bucket
#define BNODES 64
#define NB 1563                // ceil(100000/64)
#define WSW 68                 // LDS row stride (floats) for fallback GEMM
#define G 512                  // binning blocks / scanB width
#define CHUNK 2444             // per-block edge chunk, 4-aligned
#define BIN_BLOCKS 128
#define BIN_CHUNK ((N_EDGES + BIN_BLOCKS - 1) / BIN_BLOCKS)

typedef unsigned int u32;
typedef short bf16x8 __attribute__((ext_vector_type(8)));   // 8 bf16 = 4 VGPRs
typedef float f32x4 __attribute__((ext_vector_type(4)));

__device__ __forceinline__ u32 pack_bf16(float lo, float hi) {
    u32 a = __float_as_uint(lo);
    u32 b = __float_as_uint(hi);
    a = (a + 0x7fffu + ((a >> 16) & 1u)) >> 16;   // RNE
    b = (b + 0x7fffu + ((b >> 16) & 1u)) >> 16;
    return a | (b << 16);
}

// ---------------------------------------------------------------------------
// Pack B = [Wn^T | Ws^T] (64k x 128n) into MFMA B-fragment layout, bf16.
// ---------------------------------------------------------------------------
__global__ void __launch_bounds__(256) k_wprep2(const float* __restrict__ wn,
                                                const float* __restrict__ wsf,
                                                u32* __restrict__ bfrag) {
    int i = blockIdx.x * 256 + threadIdx.x;
    if (i >= 4096) return;
    int t = i >> 9, h = (i >> 8) & 1, l = (i >> 2) & 63, q = i & 3;
    int k0 = h * 32 + (l >> 4) * 8 + 2 * q;
    int n = t * 16 + (l & 15);
    const float* w = (n < 64) ? &wn[(size_t)n * 64] : &wsf[(size_t)(n - 64) * 64];
    bfrag[i] = pack_bf16(w[k0], w[k0 + 1]);
}

// ---------------------------------------------------------------------------
// Binning pass A: per-block LDS histogram -> ghist[b][g] (coalesced for scanB).
// ---------------------------------------------------------------------------
__global__ void __launch_bounds__(256) k_hist(const int* __restrict__ ei,
                                              u32* __restrict__ ghist) {
    __shared__ u32 hist[NB];
    int tid = threadIdx.x;
    int g = blockIdx.x;
    int e0 = g * CHUNK, e1 = min(e0 + CHUNK, N_EDGES);
    for (int i = tid; i < NB; i += 256) hist[i] = 0;
    __syncthreads();
    const int4* dp = (const int4*)(ei + N_EDGES + e0);
    int nv = (e1 - e0) >> 2;
    for (int i = tid; i < nv; i += 256) {
        int4 d4 = dp[i];
        atomicAdd(&hist[d4.x >> BSH], 1u);
        atomicAdd(&hist[d4.y >> BSH], 1u);
        atomicAdd(&hist[d4.z >> BSH], 1u);
        atomicAdd(&hist[d4.w >> BSH], 1u);
    }
    __syncthreads();
    for (int i = tid; i < NB; i += 256)
        ghist[(size_t)i * G + g] = hist[i];
}

// ---------------------------------------------------------------------------
// Pass B: per-bucket exclusive scan over G block counts via wave shfl-scan
// (1 barrier instead of 18); bcnt[b] = total.
// ---------------------------------------------------------------------------
__global__ void __launch_bounds__(512) k_scanB(const u32* __restrict__ ghist,
                                               u32* __restrict__ gbase,
                                               u32* __restrict__ bcnt) {
    __shared__ u32 wt[8];
    int t = threadIdx.x;
    int b = blockIdx.x;
    int lane = t & 63, wv = t >> 6;
    u32 v = ghist[(size_t)b * G + t];
    u32 s = v;
#pragma unroll
    for (int off = 1; off < 64; off <<= 1) {
        u32 n = __shfl_up(s, off, 64);
        if (lane >= off) s += n;
    }
    if (lane == 63) wt[wv] = s;
    __syncthreads();
    u32 add = 0;
#pragma unroll
    for (int q = 0; q < 8; ++q) add += (q < wv) ? wt[q] : 0u;
    u32 incl = s + add;
    gbase[(size_t)b * G + t] = incl - v;
    if (t == G - 1) bcnt[b] = incl;
}

// ---------------------------------------------------------------------------
// Pass C: scatter into reserved per-(block,bucket) ranges. LDS cursors only.
// ---------------------------------------------------------------------------
__global__ void __launch_bounds__(256) k_scat(const int* __restrict__ ei,
                                              const u32* __restrict__ gbase,
                                              u32* __restrict__ binned,
                                              int cap) {
    __shared__ u32 cur[NB];
    int tid = threadIdx.x;
    int g = blockIdx.x;
    int e0 = g * CHUNK, e1 = min(e0 + CHUNK, N_EDGES);
    for (int i = tid; i < NB; i += 256)
        cur[i] = gbase[(size_t)i * G + g];
    __syncthreads();
    const int4* sp = (const int4*)(ei + e0);
    const int4* dp = (const int4*)(ei + N_EDGES + e0);
    int nv = (e1 - e0) >> 2;
    for (int i = tid; i < nv; i += 256) {
        int4 s4 = sp[i];
        int4 d4 = dp[i];
        int ss[4] = {s4.x, s4.y, s4.z, s4.w};
        int dd[4] = {d4.x, d4.y, d4.z, d4.w};
#pragma unroll
        for (int u = 0; u < 4; ++u) {
            int b = dd[u] >> BSH;
            u32 loc = atomicAdd(&cur[b], 1u);
            if (loc < (u32)cap)
                binned[(size_t)b * cap + loc] = ((u32)ss[u] << BSH) | (u32)(dd[u] & (BNODES - 1));
        }
    }
}

// ---------------------------------------------------------------------------
// MFMA GEMM: [Y | Z] = bf16(x) @ B. Y bf16 -> y16, Z fp32 + bias -> d_out.
// ---------------------------------------------------------------------------
__global__ void __launch_bounds__(256) k_mm(const float* __restrict__ x,
                                            const u32* __restrict__ bfrag,
                                            const float* __restrict__ bias,
                                            u32* __restrict__ y16,
                                            float* __restrict__ zout) {
    int tid = threadIdx.x;
    int w = tid >> 6, l = tid & 63;
    int lg = l >> 4, c = l & 15;
    int nodebase = blockIdx.x * 128 + w * 32;

    union FU { uint4 u; bf16x8 v; };

    bf16x8 af[2][2];
#pragma unroll
    for (int m = 0; m < 2; ++m) {
        int node = nodebase + m * 16 + c;
        if (node >= N_NODES) node = N_NODES - 1;
        const float4* xr = (const float4*)(x + (size_t)node * D);
#pragma unroll
        for (int h = 0; h < 2; ++h) {
            float4 p0 = xr[h * 8 + lg * 2];
            float4 p1 = xr[h * 8 + lg * 2 + 1];
            FU au;
            au.u.x = pack_bf16(p0.x, p0.y);
            au.u.y = pack_bf16(p0.z, p0.w);
            au.u.z = pack_bf16(p1.x, p1.y);
            au.u.w = pack_bf16(p1.z, p1.w);
            af[m][h] = au.v;
        }
    }

    f32x4 acc[2][8];
#pragma unroll
    for (int m = 0; m < 2; ++m) {
#pragma unroll
        for (int t = 0; t < 4; ++t) acc[m][t] = (f32x4){0.f, 0.f, 0.f, 0.f};
#pragma unroll
        for (int t = 4; t < 8; ++t) {
            float bb = bias[(t - 4) * 16 + c];
            acc[m][t] = (f32x4){bb, bb, bb, bb};
        }
    }

    const uint4* bp = (const uint4*)bfrag;
#pragma unroll
    for (int tc = 0; tc < 2; ++tc) {
        bf16x8 bf[4][2];
#pragma unroll
        for (int tt = 0; tt < 4; ++tt)
#pragma unroll
            for (int h = 0; h < 2; ++h) {
                FU bu;
                bu.u = bp[(((tc * 4 + tt) * 2 + h) * 64) + l];
                bf[tt][h] = bu.v;
            }
#pragma unroll
        for (int m = 0; m < 2; ++m)
#pragma unroll
            for (int tt = 0; tt < 4; ++tt) {
                int t = tc * 4 + tt;
                acc[m][t] = __builtin_amdgcn_mfma_f32_16x16x32_bf16(
                    af[m][0], bf[tt][0], acc[m][t], 0, 0, 0);
                acc[m][t] = __builtin_amdgcn_mfma_f32_16x16x32_bf16(
                    af[m][1], bf[tt][1], acc[m][t], 0, 0, 0);
            }
    }

#pragma unroll
    for (int m = 0; m < 2; ++m) {
        int rowbase = nodebase + m * 16 + lg * 4;
#pragma unroll
        for (int r = 0; r < 4; ++r) {
            int node = rowbase + r;
            bool ok = node < N_NODES;
#pragma unroll
            for (int t = 4; t < 8; ++t) {
                if (ok) zout[(size_t)node * D + (t - 4) * 16 + c] = acc[m][t][r];
            }
#pragma unroll
            for (int t = 0; t < 4; ++t) {
                float v = acc[m][t][r];
                float o = __shfl_xor(v, 1);
                if (ok && !(c & 1))
                    y16[(size_t)node * 32 + t * 8 + (c >> 1)] = pack_bf16(v, o);
            }
        }
    }
}

// ---------------------------------------------------------------------------
// Per-bucket counting sort, in place. meta[node] = (abs offset, degree).
// ---------------------------------------------------------------------------
__global__ void __launch_bounds__(256) k_sort(u32* __restrict__ binned,
                                              const u32* __restrict__ bcnt,
                                              int cap,
                                              uint2* __restrict__ meta) {
    __shared__ u32 eh[1024];
    __shared__ u32 hist[BNODES];
    __shared__ u32 cur[BNODES];
    int tid = threadIdx.x;
    int b = blockIdx.x;
    int cnt = min((int)bcnt[b], cap);
    u32* seg = binned + (size_t)b * cap;

    if (tid < BNODES) hist[tid] = 0;
    __syncthreads();
    const uint4* segv = (const uint4*)seg;
    int nv = cnt >> 2;
    for (int i = tid; i < nv; i += 256) {
        uint4 w4 = segv[i];
        *(uint4*)&eh[4 * i] = w4;
        atomicAdd(&hist[w4.x & (BNODES - 1)], 1u);
        atomicAdd(&hist[w4.y & (BNODES - 1)], 1u);
        atomicAdd(&hist[w4.z & (BNODES - 1)], 1u);
        atomicAdd(&hist[w4.w & (BNODES - 1)], 1u);
    }
    for (int i = (cnt & ~3) + tid; i < cnt; i += 256) {
        u32 w = seg[i];
        eh[i] = w;
        atomicAdd(&hist[w & (BNODES - 1)], 1u);
    }
    __syncthreads();
    if (tid < BNODES) {
        u32 v = hist[tid];
        u32 s = v;
#pragma unroll
        for (int off = 1; off < 64; off <<= 1) {
            u32 n = __shfl_up(s, off, 64);
            if (tid >= off) s += n;
        }
        u32 excl = s - v;
        cur[tid] = excl;
        int node = (b << BSH) + tid;
        if (node < N_NODES)
            meta[node] = make_uint2((u32)((size_t)b * cap + excl), v);
    }
    __syncthreads();
    for (int i = tid; i < cnt; i += 256) {
        u32 w = eh[i];
        u32 p = atomicAdd(&cur[w & (BNODES - 1)], 1u);
        seg[p] = w >> BSH;
    }
}

// ---------------------------------------------------------------------------
// Final gather: out[n] = Z[n] + mean(Y16[src]). One wave/node.
// Loads PREDICATED (exec-masked lanes issue no transactions; zero-fill keeps
// accumulation branch-free per lane); unpack+FMA clusters skipped by
// wave-uniform branch (dmain uniform per wave). 8 loads in flight.
// ---------------------------------------------------------------------------
__global__ void __launch_bounds__(256) k_gather_yz(const u32* __restrict__ y16,
                                                   const u32* __restrict__ binned,
                                                   const uint2* __restrict__ meta,
                                                   float* __restrict__ io) {
    int tid = blockIdx.x * 256 + threadIdx.x;
    int node = tid >> 6;
    if (node >= N_NODES) return;
    int lane = threadIdx.x & 63;
    int sub = lane >> 4;
    int pr = lane & 15;
    const uint2* yv = (const uint2*)y16;
    uint2 m = meta[node];
    u32 o0 = m.x, dg = m.y;

    u32 myidx = 0;
    if (lane < (int)dg) myidx = binned[o0 + lane];   // one coalesced round

    float a0 = 0.f, a1 = 0.f, a2 = 0.f, a3 = 0.f;
    u32 dmain = min(dg, 64u);
    for (u32 r = 0; r < dmain; r += 32) {
        uint2 w[8];
#pragma unroll
        for (int t = 0; t < 8; ++t) {
            u32 e = r + 4 * t + sub;
            u32 idx = (u32)__shfl((int)myidx, (int)(e & 63));
            w[t] = make_uint2(0u, 0u);
            if (e < dmain) w[t] = yv[(size_t)idx * 16 + pr];   // predicated load
        }
#pragma unroll
        for (int t = 0; t < 8; ++t) {
            if (r + 4u * (u32)t < dmain) {                     // wave-uniform skip
                a0 += __uint_as_float(w[t].x << 16);
                a1 += __uint_as_float(w[t].x & 0xffff0000u);
                a2 += __uint_as_float(w[t].y << 16);
                a3 += __uint_as_float(w[t].y & 0xffff0000u);
            }
        }
    }
    for (u32 j = o0 + 64; j < o0 + dg; j += 16) {   // deg>64 overflow (rare)
#pragma unroll
        for (int t = 0; t < 4; ++t) {
            u32 ie = j + 4 * t + sub;
            if (ie < o0 + dg) {
                u32 idx = binned[ie];
                uint2 w = yv[(size_t)idx * 16 + pr];
                a0 += __uint_as_float(w.x << 16);
                a1 += __uint_as_float(w.x & 0xffff0000u);
                a2 += __uint_as_float(w.y << 16);
                a3 += __uint_as_float(w.y & 0xffff0000u);
            }
        }
    }

    a0 += __shfl_xor(a0, 16); a1 += __shfl_xor(a1, 16);
    a2 += __shfl_xor(a2, 16); a3 += __shfl_xor(a3, 16);
    a0 += __shfl_xor(a0, 32); a1 += __shfl_xor(a1, 32);
    a2 += __shfl_xor(a2, 32); a3 += __shfl_xor(a3, 32);
    if (sub == 0) {
        float inv = 1.0f / (float)max(dg, 1u);
        float4 z = *(const float4*)&io[(size_t)node * D + 4 * pr];
        *(float4*)&io[(size_t)node * D + 4 * pr] =
            make_float4(z.x + a0 * inv, z.y + a1 * inv, z.z + a2 * inv, z.w + a3 * inv);
    }
}

// ======================= fallback path (small workspace) ====================
__global__ void __launch_bounds__(256) k_bin2(const int* __restrict__ ei,
                                              u32* __restrict__ bcnt,
                                              u32* __restrict__ binned,
                                              int cap) {
    __shared__ u32 hist[NB];
    __shared__ u32 rbase[NB];
    int tid = threadIdx.x;
    int e0 = blockIdx.x * BIN_CHUNK;
    int e1 = min(e0 + BIN_CHUNK, N_EDGES);
    const int* dstp = ei + N_EDGES;
    for (int i = tid; i < NB; i += 256) hist[i] = 0;
    __syncthreads();
    for (int e = e0 + tid; e < e1; e += 256)
        atomicAdd(&hist[dstp[e] >> BSH], 1u);
    __syncthreads();
    for (int i = tid; i < NB; i += 256) {
        u32 h = hist[i];
        rbase[i] = h ? atomicAdd(&bcnt[i], h) : 0u;
        hist[i] = 0;
    }
    __syncthreads();
    for (int e = e0 + tid; e < e1; e += 256) {
        int d = dstp[e];
        int s = ei[e];
        int b = d >> BSH;
        u32 loc = atomicAdd(&hist[b], 1u);
        u32 slot = rbase[b] + loc;
        if (slot < (u32)cap)
            binned[(size_t)b * cap + slot] = ((u32)s << BSH) | (u32)(d & (BNODES - 1));
    }
}

__global__ void __launch_bounds__(256) k_sort_fb(u32* __restrict__ binned,
                                                 const u32* __restrict__ bcnt,
                                                 int cap,
                                                 u32* __restrict__ offs,
                                                 u32* __restrict__ deg) {
    __shared__ u32 eh[1024];
    __shared__ u32 hist[BNODES];
    __shared__ u32 cur[BNODES];
    int tid = threadIdx.x;
    int b = blockIdx.x;
    int cnt = min((int)bcnt[b], cap);
    u32* seg = binned + (size_t)b * cap;
    if (tid < BNODES) hist[tid] = 0;
    __syncthreads();
    for (int i = tid; i < cnt; i += 256) {
        u32 w = seg[i];
        eh[i] = w;
        atomicAdd(&hist[w & (BNODES - 1)], 1u);
    }
    __syncthreads();
    if (tid < BNODES) {
        u32 v = hist[tid];
        u32 s = v;
#pragma unroll
        for (int off = 1; off < 64; off <<= 1) {
            u32 n = __shfl_up(s, off, 64);
            if (tid >= off) s += n;
        }
        u32 excl = s - v;
        cur[tid] = excl;
        int node = (b << BSH) + tid;
        if (node < N_NODES) {
            offs[node] = (u32)((size_t)b * cap + excl);
            deg[node] = v;
        }
    }
    __syncthreads();
    for (int i = tid; i < cnt; i += 256) {
        u32 w = eh[i];
        u32 p = atomicAdd(&cur[w & (BNODES - 1)], 1u);
        seg[p] = w >> BSH;
    }
}

__global__ void __launch_bounds__(256) k_gather32(const float* __restrict__ x,
                                                  const u32* __restrict__ binned,
                                                  const u32* __restrict__ offs,
                                                  const u32* __restrict__ deg,
                                                  float* __restrict__ agg) {
    int tid = blockIdx.x * 256 + threadIdx.x;
    int node = tid >> 6;
    int d = tid & 63;
    if (node >= N_NODES) return;
    u32 o0 = offs[node], dg = deg[node];
    u32 o1 = o0 + dg;
    float s = 0.f;
    u32 j = o0;
    for (; j + 8 <= o1; j += 8) {
        u32 e[8];
        float v[8];
#pragma unroll
        for (int t = 0; t < 8; ++t) e[t] = binned[j + t];
#pragma unroll
        for (int t = 0; t < 8; ++t) v[t] = x[(size_t)e[t] * D + d];
#pragma unroll
        for (int t = 0; t < 8; ++t) s += v[t];
    }
    for (; j < o1; ++j) s += x[(size_t)binned[j] * D + d];
    agg[(size_t)node * D + d] = s / (float)max(dg, 1u);
}

__global__ void __launch_bounds__(256) k_gemm_fb(const float* __restrict__ x,
                                                 const float* __restrict__ wn,
                                                 const float* __restrict__ wsf,
                                                 const float* __restrict__ bias,
                                                 float* __restrict__ io) {
    __shared__ float At[BNODES * WSW];
    __shared__ float Wt[128 * WSW];
    int tid = threadIdx.x;
    int base = blockIdx.x * 64;
    const float4* iop = (const float4*)io;
    const float4* xp  = (const float4*)x;
    for (int i = tid; i < 4096; i += 256) {
        int d = i >> 6, k = i & 63;
        Wt[k * WSW + d] = wn[i];
        Wt[(64 + k) * WSW + d] = wsf[i];
    }
    for (int i = tid; i < 1024; i += 256) {
        int r = i >> 4, q = i & 15;
        int node = base + r;
        float4 v = make_float4(0.f, 0.f, 0.f, 0.f);
        if (node < N_NODES) v = iop[(size_t)node * 16 + q];
        *(float4*)&At[r * WSW + q * 4] = v;
    }
    __syncthreads();
    int tn = tid >> 4, td = tid & 15;
    int n0 = tn * 4, d0 = td * 4;
    float4 b4 = *(const float4*)&bias[d0];
    float acc[4][4];
#pragma unroll
    for (int i = 0; i < 4; ++i) {
        acc[i][0] = b4.x; acc[i][1] = b4.y; acc[i][2] = b4.z; acc[i][3] = b4.w;
    }
#pragma unroll 8
    for (int kc = 0; kc < 16; ++kc) {
        float4 a[4], w[4];
#pragma unroll
        for (int i = 0; i < 4; ++i) a[i] = *(const float4*)&At[(n0 + i) * WSW + kc * 4];
#pragma unroll
        for (int t = 0; t < 4; ++t) w[t] = *(const float4*)&Wt[(kc * 4 + t) * WSW + d0];
#pragma unroll
        for (int i = 0; i < 4; ++i) {
            const float av[4] = {a[i].x, a[i].y, a[i].z, a[i].w};
#pragma unroll
            for (int t = 0; t < 4; ++t) {
                acc[i][0] += av[t] * w[t].x; acc[i][1] += av[t] * w[t].y;
                acc[i][2] += av[t] * w[t].z; acc[i][3] += av[t] * w[t].w;
            }
        }
    }
    __syncthreads();
    for (int i = tid; i < 1024; i += 256) {
        int r = i >> 4, q = i & 15;
        int node = base + r;
        float4 v = make_float4(0.f, 0.f, 0.f, 0.f);
        if (node < N_NODES) v = xp[(size_t)node * 16 + q];
        *(float4*)&At[r * WSW + q * 4] = v;
    }
    __syncthreads();
#pragma unroll 8
    for (int kc = 0; kc < 16; ++kc) {
        float4 a[4], w[4];
#pragma unroll
        for (int i = 0; i < 4; ++i) a[i] = *(const float4*)&At[(n0 + i) * WSW + kc * 4];
#pragma unroll
        for (int t = 0; t < 4; ++t) w[t] = *(const float4*)&Wt[(64 + kc * 4 + t) * WSW + d0];
#pragma unroll
        for (int i = 0; i < 4; ++i) {
            const float av[4] = {a[i].x, a[i].y, a[i].z, a[i].w};
#pragma unroll
            for (int t = 0; t < 4; ++t) {
                acc[i][0] += av[t] * w[t].x; acc[i][1] += av[t] * w[t].y;
                acc[i][2] += av[t] * w[t].z; acc[i][3] += av[t] * w[t].w;
            }
        }
    }
#pragma unroll
    for (int i = 0; i < 4; ++i) {
        int node = base + n0 + i;
        if (node < N_NODES) {
            *(float4*)&io[(size_t)node * D + d0] =
                make_float4(acc[i][0], acc[i][1], acc[i][2], acc[i][3]);
        }
    }
}

extern "C" void kernel_launch(void* const* d_in, const int* in_sizes, int n_in,
                              void* d_out, int out_size, void* d_ws, size_t ws_size,
                              hipStream_t stream) {
    const float* x = (const float*)d_in[0];
    const int* ei = (const int*)d_in[1];
    const float* wn = (const float*)d_in[2];
    const float* wsf = (const float*)d_in[3];
    const float* bias = (const float*)d_in[4];
    float* out = (float*)d_out;

    // ws layout (u32): meta[200000] bcnt[1568] bfrag[8192] y16[3.2M] binned[NB*1024]
    u32* metaw = (u32*)d_ws;
    u32* bcnt = metaw + 2 * N_NODES;
    u32* bfrag = bcnt + ((NB + 15) & ~15);
    u32* y16 = bfrag + 8192;
    const size_t Y16W = (size_t)N_NODES * (D / 2);
    u32* binned = y16 + Y16W;
    size_t fixed = 2 * (size_t)N_NODES + ((NB + 15) & ~15) + 8192;

    if (ws_size / 4 >= fixed + Y16W + (size_t)NB * 1024) {
        const int cap = 1024;
        // Aliases (dead before their hosts are written):
        u32* ghist = binned;   // NB*G = 800K u32 <= NB*cap; dead before k_scat writes binned
        u32* gbase = y16;      // NB*G = 800K u32 <= Y16W;   dead before k_mm writes y16
        k_wprep2<<<16, 256, 0, stream>>>(wn, wsf, bfrag);
        k_hist<<<G, 256, 0, stream>>>(ei, ghist);
        k_scanB<<<NB, 512, 0, stream>>>(ghist, gbase, bcnt);
        k_scat<<<G, 256, 0, stream>>>(ei, gbase, binned, cap);
        k_mm<<<(N_NODES + 127) / 128, 256, 0, stream>>>(x, bfrag, bias, y16, out);
        k_sort<<<NB, 256, 0, stream>>>(binned, bcnt, cap, (uint2*)metaw);
        k_gather_yz<<<(N_NODES * 64) / 256, 256, 0, stream>>>(y16, binned, (const uint2*)metaw, out);
    } else {
        // Fallback: fp32 path.
        u32* offs = metaw;
        u32* deg = offs + N_NODES;
        binned = bfrag;
        size_t avail = ws_size / 4 - (fixed - 8192);
        size_t capz = (avail / NB) & ~(size_t)3;
        int cap = (int)(capz < 1024 ? capz : 1024);
        hipMemsetAsync(bcnt, 0, ((NB + 15) & ~15) * sizeof(u32), stream);
        k_bin2<<<BIN_BLOCKS, 256, 0, stream>>>(ei, bcnt, binned, cap);
        k_sort_fb<<<NB, 256, 0, stream>>>(binned, bcnt, cap, offs, deg);
        k_gather32<<<(N_NODES * 64) / 256, 256, 0, stream>>>(x, binned, offs, deg, out);
        k_gemm_fb<<<(N_NODES + 63) / 64, 256, 0, stream>>>(x, wn, wsf, bias, out);
    }
}

// Round 12
// 91.176 us; speedup vs baseline: 6.1975x; 1.1000x over previous
//
#include <hip/hip_runtime.h>

#define N_NODES 100000
#define N_EDGES 1250000
#define D 64
#define BSH 6                  // 64 nodes per bucket
#define BNODES 64
#define NB 1563                // ceil(100000/64)
#define WSW 68                 // LDS row stride (floats) for fallback GEMM
#define G 512                  // binning blocks / scanB width
#define CHUNK 2444             // per-block edge chunk, 4-aligned
#define MM_BLOCKS ((N_NODES + 127) / 128)     // 782
#define BIN_BLOCKS 128
#define BIN_CHUNK ((N_EDGES + BIN_BLOCKS - 1) / BIN_BLOCKS)

typedef unsigned int u32;
typedef short bf16x8 __attribute__((ext_vector_type(8)));   // 8 bf16 = 4 VGPRs
typedef float f32x4 __attribute__((ext_vector_type(4)));

__device__ __forceinline__ u32 pack_bf16(float lo, float hi) {
    u32 a = __float_as_uint(lo);
    u32 b = __float_as_uint(hi);
    a = (a + 0x7fffu + ((a >> 16) & 1u)) >> 16;   // RNE
    b = (b + 0x7fffu + ((b >> 16) & 1u)) >> 16;
    return a | (b << 16);
}

// ---------------------------------------------------------------------------
// Fused: blocks 0..G-1 do binning pass A (per-block LDS histogram ->
// ghist[b][g]); block G packs B = [Wn^T|Ws^T] into MFMA B-fragment layout.
// ---------------------------------------------------------------------------
__global__ void __launch_bounds__(256) k_histw(const int* __restrict__ ei,
                                               u32* __restrict__ ghist,
                                               const float* __restrict__ wn,
                                               const float* __restrict__ wsf,
                                               u32* __restrict__ bfrag) {
    __shared__ u32 hist[NB];
    int tid = threadIdx.x;
    if (blockIdx.x < G) {
        int g = blockIdx.x;
        int e0 = g * CHUNK, e1 = min(e0 + CHUNK, N_EDGES);
        for (int i = tid; i < NB; i += 256) hist[i] = 0;
        __syncthreads();
        const int4* dp = (const int4*)(ei + N_EDGES + e0);
        int nv = (e1 - e0) >> 2;
        for (int i = tid; i < nv; i += 256) {
            int4 d4 = dp[i];
            atomicAdd(&hist[d4.x >> BSH], 1u);
            atomicAdd(&hist[d4.y >> BSH], 1u);
            atomicAdd(&hist[d4.z >> BSH], 1u);
            atomicAdd(&hist[d4.w >> BSH], 1u);
        }
        __syncthreads();
        for (int i = tid; i < NB; i += 256)
            ghist[(size_t)i * G + g] = hist[i];
    } else {
        // Weight prep: 4096 words, one block.
        for (int i = tid; i < 4096; i += 256) {
            int t = i >> 9, h = (i >> 8) & 1, l = (i >> 2) & 63, q = i & 3;
            int k0 = h * 32 + (l >> 4) * 8 + 2 * q;
            int n = t * 16 + (l & 15);
            const float* w = (n < 64) ? &wn[(size_t)n * 64] : &wsf[(size_t)(n - 64) * 64];
            bfrag[i] = pack_bf16(w[k0], w[k0 + 1]);
        }
    }
}

// ---------------------------------------------------------------------------
// Pass B: per-bucket exclusive scan over G block counts via wave shfl-scan.
// ---------------------------------------------------------------------------
__global__ void __launch_bounds__(512) k_scanB(const u32* __restrict__ ghist,
                                               u32* __restrict__ gbase,
                                               u32* __restrict__ bcnt) {
    __shared__ u32 wt[8];
    int t = threadIdx.x;
    int b = blockIdx.x;
    int lane = t & 63, wv = t >> 6;
    u32 v = ghist[(size_t)b * G + t];
    u32 s = v;
#pragma unroll
    for (int off = 1; off < 64; off <<= 1) {
        u32 n = __shfl_up(s, off, 64);
        if (lane >= off) s += n;
    }
    if (lane == 63) wt[wv] = s;
    __syncthreads();
    u32 add = 0;
#pragma unroll
    for (int q = 0; q < 8; ++q) add += (q < wv) ? wt[q] : 0u;
    u32 incl = s + add;
    gbase[(size_t)b * G + t] = incl - v;
    if (t == G - 1) bcnt[b] = incl;
}

// ---------------------------------------------------------------------------
// Fused scat || mm (independent outputs; one launch -> HW co-schedules).
// Blocks 0..G-1: scatter edges into reserved per-(block,bucket) ranges.
// Blocks G..: MFMA GEMM [Y|Z] = bf16(x) @ B; Y bf16 -> y16, Z+bias -> d_out.
// ---------------------------------------------------------------------------
__global__ void __launch_bounds__(256) k_scatmm(const int* __restrict__ ei,
                                                const u32* __restrict__ gbase,
                                                u32* __restrict__ binned,
                                                int cap,
                                                const float* __restrict__ x,
                                                const u32* __restrict__ bfrag,
                                                const float* __restrict__ bias,
                                                u32* __restrict__ y16,
                                                float* __restrict__ zout) {
    __shared__ u32 cur[NB];
    int tid = threadIdx.x;
    if (blockIdx.x < G) {
        int g = blockIdx.x;
        int e0 = g * CHUNK, e1 = min(e0 + CHUNK, N_EDGES);
        for (int i = tid; i < NB; i += 256)
            cur[i] = gbase[(size_t)i * G + g];
        __syncthreads();
        const int4* sp = (const int4*)(ei + e0);
        const int4* dp = (const int4*)(ei + N_EDGES + e0);
        int nv = (e1 - e0) >> 2;
        for (int i = tid; i < nv; i += 256) {
            int4 s4 = sp[i];
            int4 d4 = dp[i];
            int ss[4] = {s4.x, s4.y, s4.z, s4.w};
            int dd[4] = {d4.x, d4.y, d4.z, d4.w};
#pragma unroll
            for (int u = 0; u < 4; ++u) {
                int b = dd[u] >> BSH;
                u32 loc = atomicAdd(&cur[b], 1u);
                if (loc < (u32)cap)
                    binned[(size_t)b * cap + loc] = ((u32)ss[u] << BSH) | (u32)(dd[u] & (BNODES - 1));
            }
        }
        return;
    }

    // ---- MFMA GEMM part ----
    int w = tid >> 6, l = tid & 63;
    int lg = l >> 4, c = l & 15;
    int nodebase = (blockIdx.x - G) * 128 + w * 32;

    union FU { uint4 u; bf16x8 v; };

    bf16x8 af[2][2];
#pragma unroll
    for (int m = 0; m < 2; ++m) {
        int node = nodebase + m * 16 + c;
        if (node >= N_NODES) node = N_NODES - 1;
        const float4* xr = (const float4*)(x + (size_t)node * D);
#pragma unroll
        for (int h = 0; h < 2; ++h) {
            float4 p0 = xr[h * 8 + lg * 2];
            float4 p1 = xr[h * 8 + lg * 2 + 1];
            FU au;
            au.u.x = pack_bf16(p0.x, p0.y);
            au.u.y = pack_bf16(p0.z, p0.w);
            au.u.z = pack_bf16(p1.x, p1.y);
            au.u.w = pack_bf16(p1.z, p1.w);
            af[m][h] = au.v;
        }
    }

    f32x4 acc[2][8];
#pragma unroll
    for (int m = 0; m < 2; ++m) {
#pragma unroll
        for (int t = 0; t < 4; ++t) acc[m][t] = (f32x4){0.f, 0.f, 0.f, 0.f};
#pragma unroll
        for (int t = 4; t < 8; ++t) {
            float bb = bias[(t - 4) * 16 + c];
            acc[m][t] = (f32x4){bb, bb, bb, bb};
        }
    }

    const uint4* bp = (const uint4*)bfrag;
#pragma unroll
    for (int tc = 0; tc < 2; ++tc) {
        bf16x8 bf[4][2];
#pragma unroll
        for (int tt = 0; tt < 4; ++tt)
#pragma unroll
            for (int h = 0; h < 2; ++h) {
                FU bu;
                bu.u = bp[(((tc * 4 + tt) * 2 + h) * 64) + l];
                bf[tt][h] = bu.v;
            }
#pragma unroll
        for (int m = 0; m < 2; ++m)
#pragma unroll
            for (int tt = 0; tt < 4; ++tt) {
                int t = tc * 4 + tt;
                acc[m][t] = __builtin_amdgcn_mfma_f32_16x16x32_bf16(
                    af[m][0], bf[tt][0], acc[m][t], 0, 0, 0);
                acc[m][t] = __builtin_amdgcn_mfma_f32_16x16x32_bf16(
                    af[m][1], bf[tt][1], acc[m][t], 0, 0, 0);
            }
    }

#pragma unroll
    for (int m = 0; m < 2; ++m) {
        int rowbase = nodebase + m * 16 + lg * 4;
#pragma unroll
        for (int r = 0; r < 4; ++r) {
            int node = rowbase + r;
            bool ok = node < N_NODES;
#pragma unroll
            for (int t = 4; t < 8; ++t) {
                if (ok) zout[(size_t)node * D + (t - 4) * 16 + c] = acc[m][t][r];
            }
#pragma unroll
            for (int t = 0; t < 4; ++t) {
                float v = acc[m][t][r];
                float o = __shfl_xor(v, 1);
                if (ok && !(c & 1))
                    y16[(size_t)node * 32 + t * 8 + (c >> 1)] = pack_bf16(v, o);
            }
        }
    }
}

// ---------------------------------------------------------------------------
// Per-bucket counting sort, in place. meta[node] = (abs offset, degree).
// ---------------------------------------------------------------------------
__global__ void __launch_bounds__(256) k_sort(u32* __restrict__ binned,
                                              const u32* __restrict__ bcnt,
                                              int cap,
                                              uint2* __restrict__ meta) {
    __shared__ u32 eh[1024];
    __shared__ u32 hist[BNODES];
    __shared__ u32 cur[BNODES];
    int tid = threadIdx.x;
    int b = blockIdx.x;
    int cnt = min((int)bcnt[b], cap);
    u32* seg = binned + (size_t)b * cap;

    if (tid < BNODES) hist[tid] = 0;
    __syncthreads();
    const uint4* segv = (const uint4*)seg;
    int nv = cnt >> 2;
    for (int i = tid; i < nv; i += 256) {
        uint4 w4 = segv[i];
        *(uint4*)&eh[4 * i] = w4;
        atomicAdd(&hist[w4.x & (BNODES - 1)], 1u);
        atomicAdd(&hist[w4.y & (BNODES - 1)], 1u);
        atomicAdd(&hist[w4.z & (BNODES - 1)], 1u);
        atomicAdd(&hist[w4.w & (BNODES - 1)], 1u);
    }
    for (int i = (cnt & ~3) + tid; i < cnt; i += 256) {
        u32 w = seg[i];
        eh[i] = w;
        atomicAdd(&hist[w & (BNODES - 1)], 1u);
    }
    __syncthreads();
    if (tid < BNODES) {
        u32 v = hist[tid];
        u32 s = v;
#pragma unroll
        for (int off = 1; off < 64; off <<= 1) {
            u32 n = __shfl_up(s, off, 64);
            if (tid >= off) s += n;
        }
        u32 excl = s - v;
        cur[tid] = excl;
        int node = (b << BSH) + tid;
        if (node < N_NODES)
            meta[node] = make_uint2((u32)((size_t)b * cap + excl), v);
    }
    __syncthreads();
    for (int i = tid; i < cnt; i += 256) {
        u32 w = eh[i];
        u32 p = atomicAdd(&cur[w & (BNODES - 1)], 1u);
        seg[p] = w >> BSH;
    }
}

// ---------------------------------------------------------------------------
// Final gather: out[n] = Z[n] + mean(Y16[src]). One wave/node; one coalesced
// binned round + __shfl index distribution; predicated loads; wave-uniform
// cluster skip.
// ---------------------------------------------------------------------------
__global__ void __launch_bounds__(256) k_gather_yz(const u32* __restrict__ y16,
                                                   const u32* __restrict__ binned,
                                                   const uint2* __restrict__ meta,
                                                   float* __restrict__ io) {
    int tid = blockIdx.x * 256 + threadIdx.x;
    int node = tid >> 6;
    if (node >= N_NODES) return;
    int lane = threadIdx.x & 63;
    int sub = lane >> 4;
    int pr = lane & 15;
    const uint2* yv = (const uint2*)y16;
    uint2 m = meta[node];
    u32 o0 = m.x, dg = m.y;

    u32 myidx = 0;
    if (lane < (int)dg) myidx = binned[o0 + lane];

    float a0 = 0.f, a1 = 0.f, a2 = 0.f, a3 = 0.f;
    u32 dmain = min(dg, 64u);
    for (u32 r = 0; r < dmain; r += 32) {
        uint2 w[8];
#pragma unroll
        for (int t = 0; t < 8; ++t) {
            u32 e = r + 4 * t + sub;
            u32 idx = (u32)__shfl((int)myidx, (int)(e & 63));
            w[t] = make_uint2(0u, 0u);
            if (e < dmain) w[t] = yv[(size_t)idx * 16 + pr];
        }
#pragma unroll
        for (int t = 0; t < 8; ++t) {
            if (r + 4u * (u32)t < dmain) {
                a0 += __uint_as_float(w[t].x << 16);
                a1 += __uint_as_float(w[t].x & 0xffff0000u);
                a2 += __uint_as_float(w[t].y << 16);
                a3 += __uint_as_float(w[t].y & 0xffff0000u);
            }
        }
    }
    for (u32 j = o0 + 64; j < o0 + dg; j += 16) {   // deg>64 overflow (rare)
#pragma unroll
        for (int t = 0; t < 4; ++t) {
            u32 ie = j + 4 * t + sub;
            if (ie < o0 + dg) {
                u32 idx = binned[ie];
                uint2 w = yv[(size_t)idx * 16 + pr];
                a0 += __uint_as_float(w.x << 16);
                a1 += __uint_as_float(w.x & 0xffff0000u);
                a2 += __uint_as_float(w.y << 16);
                a3 += __uint_as_float(w.y & 0xffff0000u);
            }
        }
    }

    a0 += __shfl_xor(a0, 16); a1 += __shfl_xor(a1, 16);
    a2 += __shfl_xor(a2, 16); a3 += __shfl_xor(a3, 16);
    a0 += __shfl_xor(a0, 32); a1 += __shfl_xor(a1, 32);
    a2 += __shfl_xor(a2, 32); a3 += __shfl_xor(a3, 32);
    if (sub == 0) {
        float inv = 1.0f / (float)max(dg, 1u);
        float4 z = *(const float4*)&io[(size_t)node * D + 4 * pr];
        *(float4*)&io[(size_t)node * D + 4 * pr] =
            make_float4(z.x + a0 * inv, z.y + a1 * inv, z.z + a2 * inv, z.w + a3 * inv);
    }
}

// ======================= fallback path (small workspace) ====================
__global__ void __launch_bounds__(256) k_bin2(const int* __restrict__ ei,
                                              u32* __restrict__ bcnt,
                                              u32* __restrict__ binned,
                                              int cap) {
    __shared__ u32 hist[NB];
    __shared__ u32 rbase[NB];
    int tid = threadIdx.x;
    int e0 = blockIdx.x * BIN_CHUNK;
    int e1 = min(e0 + BIN_CHUNK, N_EDGES);
    const int* dstp = ei + N_EDGES;
    for (int i = tid; i < NB; i += 256) hist[i] = 0;
    __syncthreads();
    for (int e = e0 + tid; e < e1; e += 256)
        atomicAdd(&hist[dstp[e] >> BSH], 1u);
    __syncthreads();
    for (int i = tid; i < NB; i += 256) {
        u32 h = hist[i];
        rbase[i] = h ? atomicAdd(&bcnt[i], h) : 0u;
        hist[i] = 0;
    }
    __syncthreads();
    for (int e = e0 + tid; e < e1; e += 256) {
        int d = dstp[e];
        int s = ei[e];
        int b = d >> BSH;
        u32 loc = atomicAdd(&hist[b], 1u);
        u32 slot = rbase[b] + loc;
        if (slot < (u32)cap)
            binned[(size_t)b * cap + slot] = ((u32)s << BSH) | (u32)(d & (BNODES - 1));
    }
}

__global__ void __launch_bounds__(256) k_sort_fb(u32* __restrict__ binned,
                                                 const u32* __restrict__ bcnt,
                                                 int cap,
                                                 u32* __restrict__ offs,
                                                 u32* __restrict__ deg) {
    __shared__ u32 eh[1024];
    __shared__ u32 hist[BNODES];
    __shared__ u32 cur[BNODES];
    int tid = threadIdx.x;
    int b = blockIdx.x;
    int cnt = min((int)bcnt[b], cap);
    u32* seg = binned + (size_t)b * cap;
    if (tid < BNODES) hist[tid] = 0;
    __syncthreads();
    for (int i = tid; i < cnt; i += 256) {
        u32 w = seg[i];
        eh[i] = w;
        atomicAdd(&hist[w & (BNODES - 1)], 1u);
    }
    __syncthreads();
    if (tid < BNODES) {
        u32 v = hist[tid];
        u32 s = v;
#pragma unroll
        for (int off = 1; off < 64; off <<= 1) {
            u32 n = __shfl_up(s, off, 64);
            if (tid >= off) s += n;
        }
        u32 excl = s - v;
        cur[tid] = excl;
        int node = (b << BSH) + tid;
        if (node < N_NODES) {
            offs[node] = (u32)((size_t)b * cap + excl);
            deg[node] = v;
        }
    }
    __syncthreads();
    for (int i = tid; i < cnt; i += 256) {
        u32 w = eh[i];
        u32 p = atomicAdd(&cur[w & (BNODES - 1)], 1u);
        seg[p] = w >> BSH;
    }
}

__global__ void __launch_bounds__(256) k_gather32(const float* __restrict__ x,
                                                  const u32* __restrict__ binned,
                                                  const u32* __restrict__ offs,
                                                  const u32* __restrict__ deg,
                                                  float* __restrict__ agg) {
    int tid = blockIdx.x * 256 + threadIdx.x;
    int node = tid >> 6;
    int d = tid & 63;
    if (node >= N_NODES) return;
    u32 o0 = offs[node], dg = deg[node];
    u32 o1 = o0 + dg;
    float s = 0.f;
    u32 j = o0;
    for (; j + 8 <= o1; j += 8) {
        u32 e[8];
        float v[8];
#pragma unroll
        for (int t = 0; t < 8; ++t) e[t] = binned[j + t];
#pragma unroll
        for (int t = 0; t < 8; ++t) v[t] = x[(size_t)e[t] * D + d];
#pragma unroll
        for (int t = 0; t < 8; ++t) s += v[t];
    }
    for (; j < o1; ++j) s += x[(size_t)binned[j] * D + d];
    agg[(size_t)node * D + d] = s / (float)max(dg, 1u);
}

__global__ void __launch_bounds__(256) k_gemm_fb(const float* __restrict__ x,
                                                 const float* __restrict__ wn,
                                                 const float* __restrict__ wsf,
                                                 const float* __restrict__ bias,
                                                 float* __restrict__ io) {
    __shared__ float At[BNODES * WSW];
    __shared__ float Wt[128 * WSW];
    int tid = threadIdx.x;
    int base = blockIdx.x * 64;
    const float4* iop = (const float4*)io;
    const float4* xp  = (const float4*)x;
    for (int i = tid; i < 4096; i += 256) {
        int d = i >> 6, k = i & 63;
        Wt[k * WSW + d] = wn[i];
        Wt[(64 + k) * WSW + d] = wsf[i];
    }
    for (int i = tid; i < 1024; i += 256) {
        int r = i >> 4, q = i & 15;
        int node = base + r;
        float4 v = make_float4(0.f, 0.f, 0.f, 0.f);
        if (node < N_NODES) v = iop[(size_t)node * 16 + q];
        *(float4*)&At[r * WSW + q * 4] = v;
    }
    __syncthreads();
    int tn = tid >> 4, td = tid & 15;
    int n0 = tn * 4, d0 = td * 4;
    float4 b4 = *(const float4*)&bias[d0];
    float acc[4][4];
#pragma unroll
    for (int i = 0; i < 4; ++i) {
        acc[i][0] = b4.x; acc[i][1] = b4.y; acc[i][2] = b4.z; acc[i][3] = b4.w;
    }
#pragma unroll 8
    for (int kc = 0; kc < 16; ++kc) {
        float4 a[4], w[4];
#pragma unroll
        for (int i = 0; i < 4; ++i) a[i] = *(const float4*)&At[(n0 + i) * WSW + kc * 4];
#pragma unroll
        for (int t = 0; t < 4; ++t) w[t] = *(const float4*)&Wt[(kc * 4 + t) * WSW + d0];
#pragma unroll
        for (int i = 0; i < 4; ++i) {
            const float av[4] = {a[i].x, a[i].y, a[i].z, a[i].w};
#pragma unroll
            for (int t = 0; t < 4; ++t) {
                acc[i][0] += av[t] * w[t].x; acc[i][1] += av[t] * w[t].y;
                acc[i][2] += av[t] * w[t].z; acc[i][3] += av[t] * w[t].w;
            }
        }
    }
    __syncthreads();
    for (int i = tid; i < 1024; i += 256) {
        int r = i >> 4, q = i & 15;
        int node = base + r;
        float4 v = make_float4(0.f, 0.f, 0.f, 0.f);
        if (node < N_NODES) v = xp[(size_t)node * 16 + q];
        *(float4*)&At[r * WSW + q * 4] = v;
    }
    __syncthreads();
#pragma unroll 8
    for (int kc = 0; kc < 16; ++kc) {
        float4 a[4], w[4];
#pragma unroll
        for (int i = 0; i < 4; ++i) a[i] = *(const float4*)&At[(n0 + i) * WSW + kc * 4];
#pragma unroll
        for (int t = 0; t < 4; ++t) w[t] = *(const float4*)&Wt[(64 + kc * 4 + t) * WSW + d0];
#pragma unroll
        for (int i = 0; i < 4; ++i) {
            const float av[4] = {a[i].x, a[i].y, a[i].z, a[i].w};
#pragma unroll
            for (int t = 0; t < 4; ++t) {
                acc[i][0] += av[t] * w[t].x; acc[i][1] += av[t] * w[t].y;
                acc[i][2] += av[t] * w[t].z; acc[i][3] += av[t] * w[t].w;
            }
        }
    }
#pragma unroll
    for (int i = 0; i < 4; ++i) {
        int node = base + n0 + i;
        if (node < N_NODES) {
            *(float4*)&io[(size_t)node * D + d0] =
                make_float4(acc[i][0], acc[i][1], acc[i][2], acc[i][3]);
        }
    }
}

extern "C" void kernel_launch(void* const* d_in, const int* in_sizes, int n_in,
                              void* d_out, int out_size, void* d_ws, size_t ws_size,
                              hipStream_t stream) {
    const float* x = (const float*)d_in[0];
    const int* ei = (const int*)d_in[1];
    const float* wn = (const float*)d_in[2];
    const float* wsf = (const float*)d_in[3];
    const float* bias = (const float*)d_in[4];
    float* out = (float*)d_out;

    // ws layout (u32), no aliasing (~27 MB):
    // meta[200000] bcnt[1568] bfrag[8192] y16[3.2M] binned[NB*1024] ghist[NB*G] gbase[NB*G]
    u32* metaw = (u32*)d_ws;
    u32* bcnt = metaw + 2 * N_NODES;
    u32* bfrag = bcnt + ((NB + 15) & ~15);
    u32* y16 = bfrag + 8192;
    const size_t Y16W = (size_t)N_NODES * (D / 2);
    u32* binned = y16 + Y16W;
    u32* ghist = binned + (size_t)NB * 1024;
    u32* gbase = ghist + (size_t)NB * G;
    size_t fixed = 2 * (size_t)N_NODES + ((NB + 15) & ~15) + 8192;
    size_t need = fixed + Y16W + (size_t)NB * 1024 + 2 * (size_t)NB * G;

    if (ws_size / 4 >= need) {
        const int cap = 1024;
        k_histw<<<G + 1, 256, 0, stream>>>(ei, ghist, wn, wsf, bfrag);
        k_scanB<<<NB, 512, 0, stream>>>(ghist, gbase, bcnt);
        k_scatmm<<<G + MM_BLOCKS, 256, 0, stream>>>(ei, gbase, binned, cap,
                                                    x, bfrag, bias, y16, out);
        k_sort<<<NB, 256, 0, stream>>>(binned, bcnt, cap, (uint2*)metaw);
        k_gather_yz<<<(N_NODES * 64) / 256, 256, 0, stream>>>(y16, binned, (const uint2*)metaw, out);
    } else {
        // Fallback: fp32 path.
        u32* offs = metaw;
        u32* deg = offs + N_NODES;
        binned = bfrag;
        size_t avail = ws_size / 4 - (fixed - 8192);
        size_t capz = (avail / NB) & ~(size_t)3;
        int cap = (int)(capz < 1024 ? capz : 1024);
        hipMemsetAsync(bcnt, 0, ((NB + 15) & ~15) * sizeof(u32), stream);
        k_bin2<<<BIN_BLOCKS, 256, 0, stream>>>(ei, bcnt, binned, cap);
        k_sort_fb<<<NB, 256, 0, stream>>>(binned, bcnt, cap, offs, deg);
        k_gather32<<<(N_NODES * 64) / 256, 256, 0, stream>>>(x, binned, offs, deg, out);
        k_gemm_fb<<<(N_NODES + 63) / 64, 256, 0, stream>>>(x, wn, wsf, bias, out);
    }
}